// Round 8
// baseline (273.341 us; speedup 1.0000x reference)
//
#include <hip/hip_runtime.h>

#define DEV __device__ __forceinline__
typedef unsigned short u16;
typedef __bf16 bf16x8 __attribute__((ext_vector_type(8)));
typedef float f32x4 __attribute__((ext_vector_type(4)));

DEV u16 f2bf(float f) {                      // RNE f32 -> bf16
  unsigned u = __float_as_uint(f);
  u += 0x7FFF + ((u >> 16) & 1);
  return (u16)(u >> 16);
}
DEV float bflo(unsigned u) { return __uint_as_float(u << 16); }          // low u16 -> f32
DEV float bfhi(unsigned u) { return __uint_as_float(u & 0xFFFF0000u); }  // high u16 -> f32

// ---------------- geometry ----------------
// x    [64,3,125,125] fp32
// xp   [64,3,129,128] fp32 zero-padded
// z1t  [64,63,64,32]  bf16
// z2h/z2l [65536][64] bf16 pixel-major hi/lo (post-ReLU conv2 output)
// z3h/z3l [65536][64] bf16 pixel-major hi/lo (conv3 output; z = hi + lo)
// e_t  [64,32,32,64]  bf16  pixel-major
// h1t  [64,64,64,64]  bf16  pixel-major
// h2t  [64,128,128,32] bf16 pixel-major
// xr   [64,3,125,125] fp32
// acc[0] = vq loss sum (atomic from k_vqpf); psum = per-block recon partials

// ---------------- prep + pad fused ----------------
// blocks [0,598): weight/codebook prep. blocks [598,3694): pad x -> xp.
__global__ __launch_bounds__(256) void k_prep(
    const float* __restrict__ ew1, const float* __restrict__ ew2,
    const float* __restrict__ ew3, const float* __restrict__ dw1,
    const float* __restrict__ dw2, const float* __restrict__ dw3,
    const float* __restrict__ cb,
    float* __restrict__ wc1p, u16* __restrict__ wc3b,
    u16* __restrict__ w3f, float* __restrict__ c2,
    u16* __restrict__ w2f, u16* __restrict__ wt1f, u16* __restrict__ wt2f,
    u16* __restrict__ cbf,
    const float* __restrict__ x, float* __restrict__ xp) {
  if (blockIdx.x >= 598) {                 // ---- pad part ----
    int idx = (blockIdx.x - 598) * 256 + threadIdx.x;   // 792576 threads
    int c4 = idx & 31;
    int r  = (idx >> 5) % 129;
    int cbp = (idx >> 5) / 129;
    int ih = r - 1;
    float4 v = make_float4(0.f, 0.f, 0.f, 0.f);
    if ((unsigned)ih < 125u) {
      const float* rp = x + (cbp * 125 + ih) * 125;
      int iw0 = c4 * 4 - 1;
      if (iw0 >= 0)        v.x = rp[iw0];
      if (iw0 + 1 < 125)   v.y = rp[iw0 + 1];
      if (iw0 + 2 < 125)   v.z = rp[iw0 + 2];
      if (iw0 + 3 < 125)   v.w = rp[iw0 + 3];
    }
    *(float4*)(xp + (cbp * 129 + r) * 128 + c4 * 4) = v;
    return;
  }
  int i = blockIdx.x * 256 + threadIdx.x;
  if (i < 864) {
    int cl = i & 7; int t = i >> 3; int tap = t % 9; t /= 9; int ci = t % 3; int cog = t / 3;
    wc1p[i] = ew1[((cog * 8 + cl) * 3 + ci) * 9 + tap];
  } else if (i < 9056) {
    int j = i - 864;                        // wc3b: [hl][ks][nf][lane][8], 8192
    int jj = j & 7; int lane = (j >> 3) & 63; int nf = (j >> 9) & 3; int ks = (j >> 11) & 1; int hl = j >> 12;
    int co = (nf << 4) + (lane & 15);
    int ci = (ks << 5) + ((lane >> 4) << 3) + jj;
    float v = ew3[co * 64 + ci];
    u16 hi = f2bf(v);
    wc3b[j] = hl ? f2bf(v - __uint_as_float((unsigned)hi << 16)) : hi;
  } else if (i < 13152) {
    int j = i - 9056;                       // w3f: [hl][tp][lane][8]
    int jj = j & 7; int lane = (j >> 3) & 63; int tp = (j >> 9) & 3; int hl = j >> 11;
    int kh = tp >> 1, kw = tp & 1;
    int ci = ((lane >> 4) << 3) + jj; int co = lane & 15;
    float wv = (co < 3) ? dw3[((ci * 3 + co) * 2 + kh) * 2 + kw] : 0.f;
    u16 hi = f2bf(wv);
    if (hl == 0) w3f[j] = hi;
    else         w3f[j] = f2bf(wv - __uint_as_float((unsigned)hi << 16));
  } else if (i < 13664) {
    int k = i - 13152;
    const float4* c4 = (const float4*)(cb + (k << 6));
    float s = 0.f;
    #pragma unroll
    for (int q = 0; q < 16; ++q) { float4 v = c4[q]; s += v.x*v.x + v.y*v.y + v.z*v.z + v.w*v.w; }
    c2[k] = s;
  } else if (i < 32096) {
    int j = i - 13664;                      // w2f: [kt][nf][lane][8]
    int jj = j & 7; int lane = (j >> 3) & 63; int nf = (j >> 9) & 3; int kt = j >> 11;
    int kh = kt / 3, kw = kt % 3;
    int ci = ((lane >> 4) << 3) + jj; int co = (nf << 4) + (lane & 15);
    w2f[j] = f2bf(ew2[((co * 32 + ci) * 3 + kh) * 3 + kw]);
  } else if (i < 68960) {
    int j = i - 32096;                      // wt1f: [kt][s][nf][lane][8]
    int jj = j & 7; int lane = (j >> 3) & 63; int nf = (j >> 9) & 3; int s = (j >> 11) & 1; int kt = j >> 12;
    int kh = kt / 3, kw = kt % 3;
    int ci = (s << 5) + ((lane >> 4) << 3) + jj; int co = (nf << 4) + (lane & 15);
    wt1f[j] = f2bf(dw1[((ci * 64 + co) * 3 + kh) * 3 + kw]);
  } else if (i < 87392) {
    int j = i - 68960;                      // wt2f: [kt][s][nf][lane][8]
    int jj = j & 7; int lane = (j >> 3) & 63; int nf = (j >> 9) & 1; int s = (j >> 10) & 1; int kt = j >> 11;
    int kh = kt / 3, kw = kt % 3;
    int ci = (s << 5) + ((lane >> 4) << 3) + jj; int co = (nf << 4) + (lane & 15);
    wt2f[j] = f2bf(dw2[((ci * 32 + co) * 3 + kh) * 3 + kw]);
  } else if (i < 152928) {
    int j = i - 87392;                      // cbf: [hl][ks][nt][lane][8]
    int jj = j & 7; int lane = (j >> 3) & 63; int nt = (j >> 9) & 31; int ks = (j >> 14) & 1; int hl = j >> 15;
    int ci = (ks << 5) + ((lane >> 4) << 3) + jj;
    int code = (nt << 4) + (lane & 15);
    float v = cb[(code << 6) + ci];
    u16 hi = f2bf(v);
    cbf[j] = hl ? f2bf(v - __uint_as_float((unsigned)hi << 16)) : hi;
  }
}

// ---------------- conv1: padded input, all-co blocks, LDS wide stores ----------------
__global__ __launch_bounds__(256) void k_conv1(
    const float* __restrict__ xp, const float* __restrict__ wp,
    const float* __restrict__ bias, u16* __restrict__ z1t) {
  __shared__ u16 st[256 * 34];
  int t = threadIdx.x;
  int slab = blockIdx.x & 15, b = blockIdx.x >> 4;   // grid 1024
  int tx = t & 15, ty = (t >> 4) & 3, cg = t >> 6;
  int oh = slab * 4 + ty;
  int co0 = cg * 8;
  const float* wcg = wp + cg * 216;
  float acc[8][4];
  #pragma unroll
  for (int c = 0; c < 8; ++c) {
    float bv = bias[co0 + c];
    #pragma unroll
    for (int s = 0; s < 4; ++s) acc[c][s] = bv;
  }
  #pragma unroll
  for (int ci = 0; ci < 3; ++ci) {
    #pragma unroll
    for (int kh = 0; kh < 3; ++kh) {
      const float* rp = xp + ((b * 3 + ci) * 129 + (2 * oh + kh)) * 128 + 8 * tx;
      float4 qa = *(const float4*)rp;
      float4 qb = *(const float4*)(rp + 4);
      float v8 = rp[8];
      float v[9] = {qa.x, qa.y, qa.z, qa.w, qb.x, qb.y, qb.z, qb.w, v8};
      #pragma unroll
      for (int kw = 0; kw < 3; ++kw) {
        const float* wq = wcg + (ci * 9 + kh * 3 + kw) * 8;
        float4 wa = *(const float4*)wq;
        float4 wb = *(const float4*)(wq + 4);
        float w8[8] = {wa.x, wa.y, wa.z, wa.w, wb.x, wb.y, wb.z, wb.w};
        #pragma unroll
        for (int s = 0; s < 4; ++s) {
          float in = v[2 * s + kw];
          #pragma unroll
          for (int c = 0; c < 8; ++c) acc[c][s] = fmaf(in, w8[c], acc[c][s]);
        }
      }
    }
  }
  #pragma unroll
  for (int s = 0; s < 4; ++s) {
    bool wok = (tx * 4 + s) < 63;
    unsigned p0 = 0, p1 = 0, p2 = 0, p3 = 0;
    if (wok) {
      p0 = f2bf(fmaxf(acc[0][s], 0.f)) | ((unsigned)f2bf(fmaxf(acc[1][s], 0.f)) << 16);
      p1 = f2bf(fmaxf(acc[2][s], 0.f)) | ((unsigned)f2bf(fmaxf(acc[3][s], 0.f)) << 16);
      p2 = f2bf(fmaxf(acc[4][s], 0.f)) | ((unsigned)f2bf(fmaxf(acc[5][s], 0.f)) << 16);
      p3 = f2bf(fmaxf(acc[6][s], 0.f)) | ((unsigned)f2bf(fmaxf(acc[7][s], 0.f)) << 16);
    }
    int lpix = tx * 16 + ty * 4 + s;
    *(uint4*)&st[lpix * 34 + co0] = make_uint4(p0, p1, p2, p3);
  }
  __syncthreads();
  {
    int p = t;
    int ow = (p >> 4) * 4 + (p & 3);
    int ohl = (p >> 2) & 3;
    int oho = slab * 4 + ohl;
    if (oho < 63) {
      const u16* lp = &st[p * 34];
      uint4 a0 = *(const uint4*)(lp);
      uint4 a1 = *(const uint4*)(lp + 8);
      uint4 a2 = *(const uint4*)(lp + 16);
      uint4 a3 = *(const uint4*)(lp + 24);
      uint4* gp = (uint4*)(z1t + ((b * 63 + oho) * 64 + ow) * 32);
      gp[0] = a0; gp[1] = a1; gp[2] = a2; gp[3] = a3;
    }
  }
}

// ---------------- conv2: MFMA, XCD-swizzled; epilogue -> pixel-major hi/lo bf16 ----------------
__global__ __launch_bounds__(256) void k_conv2(
    const u16* __restrict__ z1t, const u16* __restrict__ wf,
    const float* __restrict__ bias, u16* __restrict__ z2h, u16* __restrict__ z2l) {
  __shared__ u16 sh[32 * 72];
  __shared__ u16 sl[32 * 72];
  int t = threadIdx.x;
  int lane = t & 63, wv = t >> 6;
  int n = lane & 15, q = lane >> 4;
  int raw = blockIdx.x;                           // grid 2048 = 8*256
  int wg = ((raw & 7) << 8) + (raw >> 3);         // bijective XCD swizzle
  int oh = wg & 31, b = wg >> 5;
  int xt = wv & 1, ch = wv >> 1;
  int xA = xt * 16 + n;
  f32x4 acc[2] = {{0,0,0,0},{0,0,0,0}};
  #pragma unroll
  for (int kh = 0; kh < 3; ++kh) {
    int ih = 2 * oh - 1 + kh;
    bool yok = (unsigned)ih < 63u;
    #pragma unroll
    for (int kw = 0; kw < 3; ++kw) {
      int iw = 2 * xA - 1 + kw;
      bool ok = yok && (iw >= 0);
      bf16x8 a = {};
      if (ok) a = *(const bf16x8*)(z1t + ((b * 63 + ih) * 64 + iw) * 32 + q * 8);
      int kt = kh * 3 + kw;
      const u16* wb = wf + ((kt << 2) + (ch << 1)) * 512 + lane * 8;
      bf16x8 b0 = *(const bf16x8*)wb;
      bf16x8 b1 = *(const bf16x8*)(wb + 512);
      acc[0] = __builtin_amdgcn_mfma_f32_16x16x32_bf16(a, b0, acc[0], 0, 0, 0);
      acc[1] = __builtin_amdgcn_mfma_f32_16x16x32_bf16(a, b1, acc[1], 0, 0, 0);
    }
  }
  #pragma unroll
  for (int j = 0; j < 2; ++j) {
    int co = ((ch << 1) + j) * 16 + n;
    float bv = bias[co];
    #pragma unroll
    for (int r = 0; r < 4; ++r) {
      int ow = xt * 16 + q * 4 + r;
      float v = fmaxf(acc[j][r] + bv, 0.f);
      u16 h = f2bf(v);
      u16 l = f2bf(v - __uint_as_float((unsigned)h << 16));
      sh[ow * 72 + co] = h;
      sl[ow * 72 + co] = l;
    }
  }
  __syncthreads();
  {
    int ow = t >> 3, sg = t & 7;
    uint4 hv = *(const uint4*)&sh[ow * 72 + sg * 8];
    uint4 lv = *(const uint4*)&sl[ow * 72 + sg * 8];
    long gp = ((long)(b * 1024 + oh * 32 + ow) << 6) + sg * 8;
    *(uint4*)(z2h + gp) = hv;
    *(uint4*)(z2l + gp) = lv;
  }
}

// ---------------- conv3 (1x1) as hi/lo MFMA GEMM: 128 px/block, grid 512 ----------------
__global__ __launch_bounds__(256) void k_conv3(
    const u16* __restrict__ z2h, const u16* __restrict__ z2l,
    const u16* __restrict__ wcb, const float* __restrict__ bias,
    u16* __restrict__ z3h, u16* __restrict__ z3l) {
  __shared__ u16 lh[128 * 72];
  __shared__ u16 ll[128 * 72];
  int t = threadIdx.x;
  int lane = t & 63, wv = t >> 6;
  int n = lane & 15, q = lane >> 4;
  int pxg = blockIdx.x & 7; int b = blockIdx.x >> 3;   // grid 512
  bf16x8 Ah[2][2], Al[2][2];
  #pragma unroll
  for (int mti = 0; mti < 2; ++mti) {
    int px = b * 1024 + pxg * 128 + (wv * 2 + mti) * 16 + n;
    const u16* ap = z2h + px * 64 + q * 8;
    const u16* al = z2l + px * 64 + q * 8;
    Ah[mti][0] = *(const bf16x8*)ap;  Ah[mti][1] = *(const bf16x8*)(ap + 32);
    Al[mti][0] = *(const bf16x8*)al;  Al[mti][1] = *(const bf16x8*)(al + 32);
  }
  f32x4 acc[2][4];
  #pragma unroll
  for (int nf = 0; nf < 4; ++nf) {
    const u16* wb = wcb + (nf << 9) + lane * 8;
    bf16x8 Bh0 = *(const bf16x8*)wb;
    bf16x8 Bh1 = *(const bf16x8*)(wb + 2048);
    bf16x8 Bl0 = *(const bf16x8*)(wb + 4096);
    bf16x8 Bl1 = *(const bf16x8*)(wb + 6144);
    #pragma unroll
    for (int mti = 0; mti < 2; ++mti) {
      f32x4 a = {0.f, 0.f, 0.f, 0.f};
      a = __builtin_amdgcn_mfma_f32_16x16x32_bf16(Ah[mti][0], Bh0, a, 0, 0, 0);
      a = __builtin_amdgcn_mfma_f32_16x16x32_bf16(Ah[mti][1], Bh1, a, 0, 0, 0);
      a = __builtin_amdgcn_mfma_f32_16x16x32_bf16(Al[mti][0], Bh0, a, 0, 0, 0);
      a = __builtin_amdgcn_mfma_f32_16x16x32_bf16(Al[mti][1], Bh1, a, 0, 0, 0);
      a = __builtin_amdgcn_mfma_f32_16x16x32_bf16(Ah[mti][0], Bl0, a, 0, 0, 0);
      a = __builtin_amdgcn_mfma_f32_16x16x32_bf16(Ah[mti][1], Bl1, a, 0, 0, 0);
      acc[mti][nf] = a;
    }
  }
  #pragma unroll
  for (int mti = 0; mti < 2; ++mti) {
    int pxl0 = (wv * 2 + mti) * 16 + q * 4;
    #pragma unroll
    for (int nf = 0; nf < 4; ++nf) {
      int co = (nf << 4) + n;
      float bv = bias[co];
      #pragma unroll
      for (int r = 0; r < 4; ++r) {
        float v = acc[mti][nf][r] + bv;
        u16 h = f2bf(v);
        u16 l = f2bf(v - __uint_as_float((unsigned)h << 16));
        lh[(pxl0 + r) * 72 + co] = h;
        ll[(pxl0 + r) * 72 + co] = l;
      }
    }
  }
  __syncthreads();
  {
    int p = t >> 1, half = t & 1;
    int la = p * 72 + half * 32;
    uint4 h0 = *(uint4*)&lh[la],      h1 = *(uint4*)&lh[la + 8];
    uint4 h2 = *(uint4*)&lh[la + 16], h3 = *(uint4*)&lh[la + 24];
    uint4 l0 = *(uint4*)&ll[la],      l1 = *(uint4*)&ll[la + 8];
    uint4 l2 = *(uint4*)&ll[la + 16], l3 = *(uint4*)&ll[la + 24];
    long gp = ((long)b * 1024 + pxg * 128 + p) * 64 + half * 32;
    uint4* oh = (uint4*)(z3h + gp);
    uint4* ol = (uint4*)(z3l + gp);
    oh[0] = h0; oh[1] = h1; oh[2] = h2; oh[3] = h3;
    ol[0] = l0; ol[1] = l1; ol[2] = l2; ol[3] = l3;
  }
}

// ---------------- VQ fused: argmin (MFMA hi/lo, 4-wave code split) + gather/loss/et ----------------
// grid 1024, 64 px/block, 4 mt/wave, rolled nt loop + REGISTER PREFETCH of next-nt B
// (r5's prefetch re-tried clean: same 4-mt config as r6, only the pipeline added).
__global__ __launch_bounds__(256) void k_vqpf(
    const u16* __restrict__ z3h, const u16* __restrict__ z3l,
    const u16* __restrict__ cbf, const float* __restrict__ c2v,
    const float* __restrict__ cb,
    u16* __restrict__ et, float* __restrict__ acc) {
  int t = threadIdx.x;
  int lane = t & 63, wv = t >> 6;
  int n = lane & 15, q = lane >> 4;
  int p0 = blockIdx.x * 64;
  bf16x8 Ah[4][2], Al[4][2];
  #pragma unroll
  for (int mt = 0; mt < 4; ++mt) {
    const u16* ap = z3h + (p0 + mt * 16 + n) * 64 + q * 8;
    const u16* al = z3l + (p0 + mt * 16 + n) * 64 + q * 8;
    Ah[mt][0] = *(const bf16x8*)ap;  Ah[mt][1] = *(const bf16x8*)(ap + 32);
    Al[mt][0] = *(const bf16x8*)al;  Al[mt][1] = *(const bf16x8*)(al + 32);
  }
  float bs[4][4]; int bix[4][4];
  #pragma unroll
  for (int mt = 0; mt < 4; ++mt)
    #pragma unroll
    for (int r = 0; r < 4; ++r) { bs[mt][r] = 3.4e38f; bix[mt][r] = 0; }
  const u16* bp = cbf + lane * 8;
  int ntb = wv * 8;
  bf16x8 nBh0 = *(const bf16x8*)(bp + (ntb << 9));
  bf16x8 nBh1 = *(const bf16x8*)(bp + ((32 + ntb) << 9));
  bf16x8 nBl0 = *(const bf16x8*)(bp + ((64 + ntb) << 9));
  bf16x8 nBl1 = *(const bf16x8*)(bp + ((96 + ntb) << 9));
  for (int nt0 = 0; nt0 < 8; ++nt0) {
    int nt = ntb + nt0;
    bf16x8 Bh0 = nBh0, Bh1 = nBh1, Bl0 = nBl0, Bl1 = nBl1;
    int ntn = nt + ((nt0 < 7) ? 1 : 0);       // last iter reloads same (L2-hot, harmless)
    nBh0 = *(const bf16x8*)(bp + (ntn << 9));
    nBh1 = *(const bf16x8*)(bp + ((32 + ntn) << 9));
    nBl0 = *(const bf16x8*)(bp + ((64 + ntn) << 9));
    nBl1 = *(const bf16x8*)(bp + ((96 + ntn) << 9));
    float c2 = c2v[(nt << 4) + n];
    #pragma unroll
    for (int mt = 0; mt < 4; ++mt) {
      f32x4 a = {0.f, 0.f, 0.f, 0.f};
      a = __builtin_amdgcn_mfma_f32_16x16x32_bf16(Ah[mt][0], Bh0, a, 0, 0, 0);
      a = __builtin_amdgcn_mfma_f32_16x16x32_bf16(Ah[mt][1], Bh1, a, 0, 0, 0);
      a = __builtin_amdgcn_mfma_f32_16x16x32_bf16(Al[mt][0], Bh0, a, 0, 0, 0);
      a = __builtin_amdgcn_mfma_f32_16x16x32_bf16(Al[mt][1], Bh1, a, 0, 0, 0);
      a = __builtin_amdgcn_mfma_f32_16x16x32_bf16(Ah[mt][0], Bl0, a, 0, 0, 0);
      a = __builtin_amdgcn_mfma_f32_16x16x32_bf16(Ah[mt][1], Bl1, a, 0, 0, 0);
      int idx = (nt << 4) + n;
      #pragma unroll
      for (int r = 0; r < 4; ++r) {
        float sc = fmaf(-2.f, a[r], c2);
        if (sc < bs[mt][r]) { bs[mt][r] = sc; bix[mt][r] = idx; }
      }
    }
  }
  #pragma unroll
  for (int off = 8; off > 0; off >>= 1) {
    #pragma unroll
    for (int mt = 0; mt < 4; ++mt)
      #pragma unroll
      for (int r = 0; r < 4; ++r) {
        float os = __shfl_xor(bs[mt][r], off, 16);
        int oi = __shfl_xor(bix[mt][r], off, 16);
        if (os < bs[mt][r] || (os == bs[mt][r] && oi < bix[mt][r])) {
          bs[mt][r] = os; bix[mt][r] = oi;
        }
      }
  }
  __shared__ float ls[4][64];
  __shared__ int   li[4][64];
  __shared__ int   lfin[64];
  if (n == 0) {
    #pragma unroll
    for (int mt = 0; mt < 4; ++mt)
      #pragma unroll
      for (int r = 0; r < 4; ++r) {
        int px = mt * 16 + q * 4 + r;
        ls[wv][px] = bs[mt][r];
        li[wv][px] = bix[mt][r];
      }
  }
  __syncthreads();
  if (t < 64) {
    float best = ls[0][t]; int bi = li[0][t];
    #pragma unroll
    for (int w = 1; w < 4; ++w) {
      float s = ls[w][t]; int ii = li[w][t];
      if (s < best || (s == best && ii < bi)) { best = s; bi = ii; }
    }
    lfin[t] = bi;
  }
  __syncthreads();
  // ---- phase 2: gather codebook, write et, e-q loss (z from coalesced hi/lo) ----
  int pxl = t >> 2, ciq = t & 3;            // 64 px x 4 channel-quads (16 ch each)
  int ng = p0 + pxl;
  int bi = lfin[pxl];
  const u16* zh = z3h + ((long)ng << 6) + (ciq << 4);
  const u16* zl = z3l + ((long)ng << 6) + (ciq << 4);
  uint4 h0v = *(const uint4*)zh, h1v = *(const uint4*)(zh + 8);
  uint4 l0v = *(const uint4*)zl, l1v = *(const uint4*)(zl + 8);
  unsigned hw_[8] = {h0v.x, h0v.y, h0v.z, h0v.w, h1v.x, h1v.y, h1v.z, h1v.w};
  unsigned lw_[8] = {l0v.x, l0v.y, l0v.z, l0v.w, l1v.x, l1v.y, l1v.z, l1v.w};
  const float4* cq = (const float4*)(cb + (bi << 6) + (ciq << 4));
  float lsum = 0.f;
  unsigned pk[8];
  #pragma unroll
  for (int i = 0; i < 4; ++i) {
    float4 c = cq[i];
    float z0 = bflo(hw_[2 * i])     + bflo(lw_[2 * i]);
    float z1 = bfhi(hw_[2 * i])     + bfhi(lw_[2 * i]);
    float z2 = bflo(hw_[2 * i + 1]) + bflo(lw_[2 * i + 1]);
    float z3 = bfhi(hw_[2 * i + 1]) + bfhi(lw_[2 * i + 1]);
    float df;
    df = c.x - z0; lsum = fmaf(df, df, lsum);
    df = c.y - z1; lsum = fmaf(df, df, lsum);
    df = c.z - z2; lsum = fmaf(df, df, lsum);
    df = c.w - z3; lsum = fmaf(df, df, lsum);
    pk[2 * i]     = f2bf(c.x) | ((unsigned)f2bf(c.y) << 16);
    pk[2 * i + 1] = f2bf(c.z) | ((unsigned)f2bf(c.w) << 16);
  }
  uint4* ep = (uint4*)(et + ((long)ng << 6) + (ciq << 4));
  ep[0] = make_uint4(pk[0], pk[1], pk[2], pk[3]);
  ep[1] = make_uint4(pk[4], pk[5], pk[6], pk[7]);
  __shared__ float red[256];
  red[t] = lsum; __syncthreads();
  #pragma unroll
  for (int s = 128; s > 0; s >>= 1) {
    if (t < s) red[t] += red[t + s];
    __syncthreads();
  }
  if (t == 0) atomicAdd(acc + 0, red[0]);
}

// ---------------- convT1: cog-split, LDS weights, XCD-swizzled ----------------
__global__ __launch_bounds__(256) void k_convT1(
    const u16* __restrict__ et, const u16* __restrict__ wf,
    const float* __restrict__ bias, u16* __restrict__ h1t) {
  __shared__ u16 wl[36 * 512];      // 36864 B
  __shared__ u16 st[4][64 * 34];    // 17408 B
  int t = threadIdx.x;
  int lane = t & 63, wv = t >> 6;
  int yw = wv & 1, xt = wv >> 1;
  int raw = blockIdx.x;                          // grid 1024 = 8*128
  int wg = ((raw & 7) << 7) + (raw >> 3);        // bijective XCD swizzle
  int cog = wg & 1;
  int yg = (wg >> 1) & 7;
  int b = wg >> 4;
  {
    const uint4* gw = (const uint4*)wf;
    uint4* lw = (uint4*)wl;
    #pragma unroll
    for (int k = 0; k < 9; ++k) {
      int i = t + 256 * k;
      int slot = i >> 6, within = i & 63;
      int kt = slot >> 2, j = (slot >> 1) & 1, ks = slot & 1;
      int goff = (kt << 12) + (((ks << 2) + (cog << 1) + j) << 9);
      lw[i] = gw[(goff >> 3) + within];
    }
  }
  int n = lane & 15, q = lane >> 4;
  int m = xt * 16 + n;
  __syncthreads();
  for (int iter = 0; iter < 2; ++iter) {
    int y = yg * 4 + iter * 2 + yw;
    const u16* base0 = et + (((b * 32 + y) * 32) << 6) + q * 8;
    bf16x8 P00a, P00b, P01a = {}, P01b = {}, P10a = {}, P10b = {}, P11a = {}, P11b = {};
    { const u16* p = base0 + (m << 6); P00a = *(const bf16x8*)p; P00b = *(const bf16x8*)(p + 32); }
    if (m + 1 < 32) { const u16* p = base0 + ((m + 1) << 6); P01a = *(const bf16x8*)p; P01b = *(const bf16x8*)(p + 32); }
    if (y + 1 < 32) {
      const u16* base1 = base0 + (32 << 6);
      { const u16* p = base1 + (m << 6); P10a = *(const bf16x8*)p; P10b = *(const bf16x8*)(p + 32); }
      if (m + 1 < 32) { const u16* p = base1 + ((m + 1) << 6); P11a = *(const bf16x8*)p; P11b = *(const bf16x8*)(p + 32); }
    }
    f32x4 accE[2][2] = {};  // [j][pwi]
    f32x4 accO[2][2] = {};
    #pragma unroll
    for (int kw = 0; kw < 3; ++kw) {
      int pwi = (kw == 1) ? 0 : 1;
      bf16x8 A0a = (kw == 0) ? P01a : P00a;
      bf16x8 A0b = (kw == 0) ? P01b : P00b;
      bf16x8 A1a = (kw == 0) ? P11a : P10a;
      bf16x8 A1b = (kw == 0) ? P11b : P10b;
      #pragma unroll
      for (int j = 0; j < 2; ++j) {
        const u16* wE  = wl + ((((3 + kw) << 2) + (j << 1)) << 9) + lane * 8;
        const u16* wO0 = wl + (((kw << 2) + (j << 1)) << 9) + lane * 8;
        const u16* wO2 = wl + ((((6 + kw) << 2) + (j << 1)) << 9) + lane * 8;
        bf16x8 bE0 = *(const bf16x8*)wE;
        bf16x8 bE1 = *(const bf16x8*)(wE + 512);
        accE[j][pwi] = __builtin_amdgcn_mfma_f32_16x16x32_bf16(A0a, bE0, accE[j][pwi], 0, 0, 0);
        accE[j][pwi] = __builtin_amdgcn_mfma_f32_16x16x32_bf16(A0b, bE1, accE[j][pwi], 0, 0, 0);
        bf16x8 bO00 = *(const bf16x8*)wO0;
        bf16x8 bO01 = *(const bf16x8*)(wO0 + 512);
        accO[j][pwi] = __builtin_amdgcn_mfma_f32_16x16x32_bf16(A1a, bO00, accO[j][pwi], 0, 0, 0);
        accO[j][pwi] = __builtin_amdgcn_mfma_f32_16x16x32_bf16(A1b, bO01, accO[j][pwi], 0, 0, 0);
        bf16x8 bO20 = *(const bf16x8*)wO2;
        bf16x8 bO21 = *(const bf16x8*)(wO2 + 512);
        accO[j][pwi] = __builtin_amdgcn_mfma_f32_16x16x32_bf16(A0a, bO20, accO[j][pwi], 0, 0, 0);
        accO[j][pwi] = __builtin_amdgcn_mfma_f32_16x16x32_bf16(A0b, bO21, accO[j][pwi], 0, 0, 0);
      }
    }
    #pragma unroll
    for (int j = 0; j < 2; ++j) {
      int col = j * 16 + n;
      float bv = bias[cog * 32 + col];
      #pragma unroll
      for (int pw = 0; pw < 2; ++pw)
        #pragma unroll
        for (int r = 0; r < 4; ++r) {
          int ow = 2 * (xt * 16 + q * 4 + r) + pw;
          st[yw * 2 + 0][ow * 34 + col] = f2bf(fmaxf(accE[j][pw][r] + bv, 0.f));
          st[yw * 2 + 1][ow * 34 + col] = f2bf(fmaxf(accO[j][pw][r] + bv, 0.f));
        }
    }
    __syncthreads();
    {
      int row = t >> 6, ow = t & 63;   // 4 rows x 64 ow
      const u16* lp = &st[row][ow * 34];
      uint4* gp = (uint4*)(h1t + (((b * 64 + yg * 8 + iter * 4 + row) * 64 + ow) << 6) + cog * 32);
      gp[0] = *(const uint4*)(lp);
      gp[1] = *(const uint4*)(lp + 8);
      gp[2] = *(const uint4*)(lp + 16);
      gp[3] = *(const uint4*)(lp + 24);
    }
    __syncthreads();
  }
}

// ---------------- convT2: LDS weights, 4 y-pairs/block loop, XCD-swizzled ----------------
__global__ __launch_bounds__(256) void k_convT2(
    const u16* __restrict__ h1t, const u16* __restrict__ wf,
    const float* __restrict__ bias, u16* __restrict__ h2t) {
  __shared__ u16 wl[18432];         // 36864 B
  __shared__ u16 st[2][128 * 34];   // 17408 B
  int t = threadIdx.x;
  int lane = t & 63, xt = t >> 6;
  int n = lane & 15, q = lane >> 4;
  int raw = blockIdx.x;                          // grid 1024 = 8*128
  int wg = ((raw & 7) << 7) + (raw >> 3);        // bijective XCD swizzle
  int yg = wg & 15, b = wg >> 4;
  {
    const uint4* gw = (const uint4*)wf;
    uint4* lw = (uint4*)wl;
    #pragma unroll
    for (int k = 0; k < 9; ++k) lw[t + 256 * k] = gw[t + 256 * k];
  }
  int m = xt * 16 + n;
  __syncthreads();
  for (int yp = 0; yp < 4; ++yp) {
    int y = yg * 4 + yp;
    const u16* base0 = h1t + (((b * 64 + y) * 64) << 6) + q * 8;
    bf16x8 P00a, P00b, P01a = {}, P01b = {}, P10a = {}, P10b = {}, P11a = {}, P11b = {};
    { const u16* p = base0 + (m << 6); P00a = *(const bf16x8*)p; P00b = *(const bf16x8*)(p + 32); }
    if (m + 1 < 64) { const u16* p = base0 + ((m + 1) << 6); P01a = *(const bf16x8*)p; P01b = *(const bf16x8*)(p + 32); }
    if (y + 1 < 64) {
      const u16* base1 = base0 + (64 << 6);
      { const u16* p = base1 + (m << 6); P10a = *(const bf16x8*)p; P10b = *(const bf16x8*)(p + 32); }
      if (m + 1 < 64) { const u16* p = base1 + ((m + 1) << 6); P11a = *(const bf16x8*)p; P11b = *(const bf16x8*)(p + 32); }
    }
    f32x4 accE[2][2] = {};  // [nf][pwi]
    f32x4 accO[2][2] = {};
    #pragma unroll
    for (int kw = 0; kw < 3; ++kw) {
      int pwi = (kw == 1) ? 0 : 1;
      bf16x8 A0a = (kw == 0) ? P01a : P00a;
      bf16x8 A0b = (kw == 0) ? P01b : P00b;
      bf16x8 A1a = (kw == 0) ? P11a : P10a;
      bf16x8 A1b = (kw == 0) ? P11b : P10b;
      const u16* wbE = wl + ((3 + kw) << 11) + lane * 8;
      const u16* wbO0 = wl + (kw << 11) + lane * 8;
      const u16* wbO2 = wl + ((6 + kw) << 11) + lane * 8;
      #pragma unroll
      for (int nf = 0; nf < 2; ++nf) {
        bf16x8 bE0 = *(const bf16x8*)(wbE + nf * 512);
        bf16x8 bE1 = *(const bf16x8*)(wbE + (2 + nf) * 512);
        accE[nf][pwi] = __builtin_amdgcn_mfma_f32_16x16x32_bf16(A0a, bE0, accE[nf][pwi], 0, 0, 0);
        accE[nf][pwi] = __builtin_amdgcn_mfma_f32_16x16x32_bf16(A0b, bE1, accE[nf][pwi], 0, 0, 0);
        bf16x8 bO00 = *(const bf16x8*)(wbO0 + nf * 512);
        bf16x8 bO01 = *(const bf16x8*)(wbO0 + (2 + nf) * 512);
        accO[nf][pwi] = __builtin_amdgcn_mfma_f32_16x16x32_bf16(A1a, bO00, accO[nf][pwi], 0, 0, 0);
        accO[nf][pwi] = __builtin_amdgcn_mfma_f32_16x16x32_bf16(A1b, bO01, accO[nf][pwi], 0, 0, 0);
        bf16x8 bO20 = *(const bf16x8*)(wbO2 + nf * 512);
        bf16x8 bO21 = *(const bf16x8*)(wbO2 + (2 + nf) * 512);
        accO[nf][pwi] = __builtin_amdgcn_mfma_f32_16x16x32_bf16(A0a, bO20, accO[nf][pwi], 0, 0, 0);
        accO[nf][pwi] = __builtin_amdgcn_mfma_f32_16x16x32_bf16(A0b, bO21, accO[nf][pwi], 0, 0, 0);
      }
    }
    #pragma unroll
    for (int nf = 0; nf < 2; ++nf) {
      int co = nf * 16 + n;
      float bv = bias[co];
      #pragma unroll
      for (int pw = 0; pw < 2; ++pw)
        #pragma unroll
        for (int r = 0; r < 4; ++r) {
          int ow = 2 * (xt * 16 + q * 4 + r) + pw;
          st[0][ow * 34 + co] = f2bf(fmaxf(accE[nf][pw][r] + bv, 0.f));
          st[1][ow * 34 + co] = f2bf(fmaxf(accO[nf][pw][r] + bv, 0.f));
        }
    }
    __syncthreads();
    {
      int ow = t >> 1, sg = t & 1;
      #pragma unroll
      for (int l = 0; l < 2; ++l) {
        const u16* lp = &st[l][ow * 34 + sg * 16];
        unsigned w0 = *(const unsigned*)(lp + 0), w1 = *(const unsigned*)(lp + 2);
        unsigned w2 = *(const unsigned*)(lp + 4), w3 = *(const unsigned*)(lp + 6);
        unsigned w4 = *(const unsigned*)(lp + 8), w5 = *(const unsigned*)(lp + 10);
        unsigned w6 = *(const unsigned*)(lp + 12), w7 = *(const unsigned*)(lp + 14);
        uint4* gp = (uint4*)(h2t + ((((b * 128 + yg * 8 + yp * 2 + l) * 128) + ow) << 5) + sg * 16);
        gp[0] = make_uint4(w0, w1, w2, w3);
        gp[1] = make_uint4(w4, w5, w6, w7);
      }
    }
    __syncthreads();
  }
}

// ---------------- convT3 + recon loss: 5-rows-once, 4 indep MFMA chains ----------------
// grid 2048 = 64 b x 32 row-groups, XCD-swizzled. psum partials + k_fin (no fences).
__global__ __launch_bounds__(256) void k_convT3(
    const u16* __restrict__ h2t, const u16* __restrict__ w3f,
    const float* __restrict__ bias, const float* __restrict__ x,
    float* __restrict__ xr, float* __restrict__ psum) {
  int t = threadIdx.x;
  int lane = t & 63, wv = t >> 6;
  int n = lane & 15, q = lane >> 4;
  int raw = blockIdx.x;                          // grid 2048 = 8*256
  int wg = ((raw & 7) << 8) + (raw >> 3);        // bijective XCD swizzle
  int rg = wg & 31, b = wg >> 5;
  int oh0 = rg * 4;
  const u16* wbp = w3f + lane * 8;
  bf16x8 Bh0 = *(const bf16x8*)(wbp);
  bf16x8 Bh1 = *(const bf16x8*)(wbp + 512);
  bf16x8 Bh2 = *(const bf16x8*)(wbp + 1024);
  bf16x8 Bh3 = *(const bf16x8*)(wbp + 1536);
  bf16x8 Bl0 = *(const bf16x8*)(wbp + 2048);
  bf16x8 Bl1 = *(const bf16x8*)(wbp + 2560);
  bf16x8 Bl2 = *(const bf16x8*)(wbp + 3072);
  bf16x8 Bl3 = *(const bf16x8*)(wbp + 3584);
  float bv = (n < 3) ? bias[n] : 0.f;
  float lsum = 0.f;
  if (oh0 <= 121) {
    const u16* rbase = h2t + (((long)b * 128 + (oh0 + 1)) << 12) + q * 8;
    #pragma unroll
    for (int ti = 0; ti < 2; ++ti) {
      int tt = wv + ti * 4;
      int c1 = tt * 16 + n + 1;
      int c2 = c1 + 1;
      bf16x8 A[5][2];
      #pragma unroll
      for (int j = 0; j < 5; ++j) {
        A[j][0] = (bf16x8){}; A[j][1] = (bf16x8){};
        const u16* rp = rbase + ((long)j << 12);
        if (c1 < 128) A[j][0] = *(const bf16x8*)(rp + (c1 << 5));
        if (c2 < 128) A[j][1] = *(const bf16x8*)(rp + (c2 << 5));
      }
      f32x4 ac[4] = {};
      #pragma unroll
      for (int k = 0; k < 4; ++k) {
        ac[k] = __builtin_amdgcn_mfma_f32_16x16x32_bf16(A[k][0],     Bh3, ac[k], 0, 0, 0);
        ac[k] = __builtin_amdgcn_mfma_f32_16x16x32_bf16(A[k][1],     Bh2, ac[k], 0, 0, 0);
        ac[k] = __builtin_amdgcn_mfma_f32_16x16x32_bf16(A[k + 1][0], Bh1, ac[k], 0, 0, 0);
        ac[k] = __builtin_amdgcn_mfma_f32_16x16x32_bf16(A[k + 1][1], Bh0, ac[k], 0, 0, 0);
        ac[k] = __builtin_amdgcn_mfma_f32_16x16x32_bf16(A[k][0],     Bl3, ac[k], 0, 0, 0);
        ac[k] = __builtin_amdgcn_mfma_f32_16x16x32_bf16(A[k][1],     Bl2, ac[k], 0, 0, 0);
        ac[k] = __builtin_amdgcn_mfma_f32_16x16x32_bf16(A[k + 1][0], Bl1, ac[k], 0, 0, 0);
        ac[k] = __builtin_amdgcn_mfma_f32_16x16x32_bf16(A[k + 1][1], Bl0, ac[k], 0, 0, 0);
      }
      if (n < 3) {
        int ow0 = tt * 16 + q * 4;
        #pragma unroll
        for (int k = 0; k < 4; ++k) {
          int oh = oh0 + k;
          int o = b * 46875 + n * 15625 + oh * 125 + ow0;
          if (ow0 + 3 < 125) {
            float4 v = make_float4(ac[k][0] + bv, ac[k][1] + bv, ac[k][2] + bv, ac[k][3] + bv);
            float4 xv = *(const float4*)(x + o);
            *(float4*)(xr + o) = v;
            float d0 = v.x - xv.x, d1 = v.y - xv.y, d2 = v.z - xv.z, d3 = v.w - xv.w;
            lsum += d0 * d0 + d1 * d1 + d2 * d2 + d3 * d3;
          } else {
            #pragma unroll
            for (int r = 0; r < 4; ++r) {
              if (ow0 + r < 125) {
                float v = ac[k][r] + bv;
                xr[o + r] = v;
                float d = v - x[o + r];
                lsum = fmaf(d, d, lsum);
              }
            }
          }
        }
      }
    }
  } else {
    int oh = 124;
    const u16* row1 = h2t + (((long)b * 128 + (oh + 1)) << 12) + q * 8;
    const u16* row2 = row1 + 4096;
    #pragma unroll
    for (int ti = 0; ti < 2; ++ti) {
      int tt = wv + ti * 4;
      int c1 = tt * 16 + n + 1;
      int c2 = c1 + 1;
      bf16x8 a11 = {}, a12 = {}, a21 = {}, a22 = {};
      if (c1 < 128) { a11 = *(const bf16x8*)(row1 + (c1 << 5));
                      a21 = *(const bf16x8*)(row2 + (c1 << 5)); }
      if (c2 < 128) { a12 = *(const bf16x8*)(row1 + (c2 << 5));
                      a22 = *(const bf16x8*)(row2 + (c2 << 5)); }
      f32x4 a = {0.f, 0.f, 0.f, 0.f};
      a = __builtin_amdgcn_mfma_f32_16x16x32_bf16(a11, Bh3, a, 0, 0, 0);
      a = __builtin_amdgcn_mfma_f32_16x16x32_bf16(a12, Bh2, a, 0, 0, 0);
      a = __builtin_amdgcn_mfma_f32_16x16x32_bf16(a21, Bh1, a, 0, 0, 0);
      a = __builtin_amdgcn_mfma_f32_16x16x32_bf16(a22, Bh0, a, 0, 0, 0);
      a = __builtin_amdgcn_mfma_f32_16x16x32_bf16(a11, Bl3, a, 0, 0, 0);
      a = __builtin_amdgcn_mfma_f32_16x16x32_bf16(a12, Bl2, a, 0, 0, 0);
      a = __builtin_amdgcn_mfma_f32_16x16x32_bf16(a21, Bl1, a, 0, 0, 0);
      a = __builtin_amdgcn_mfma_f32_16x16x32_bf16(a22, Bl0, a, 0, 0, 0);
      if (n < 3) {
        int ow0 = tt * 16 + q * 4;
        int o = b * 46875 + n * 15625 + oh * 125 + ow0;
        if (ow0 + 3 < 125) {
          float4 v = make_float4(a[0] + bv, a[1] + bv, a[2] + bv, a[3] + bv);
          float4 xv = *(const float4*)(x + o);
          *(float4*)(xr + o) = v;
          float d0 = v.x - xv.x, d1 = v.y - xv.y, d2 = v.z - xv.z, d3 = v.w - xv.w;
          lsum += d0 * d0 + d1 * d1 + d2 * d2 + d3 * d3;
        } else {
          #pragma unroll
          for (int r = 0; r < 4; ++r) {
            if (ow0 + r < 125) {
              float v = a[r] + bv;
              xr[o + r] = v;
              float d = v - x[o + r];
              lsum = fmaf(d, d, lsum);
            }
          }
        }
      }
    }
  }
  __shared__ float red[256];
  red[t] = lsum; __syncthreads();
  #pragma unroll
  for (int s = 128; s > 0; s >>= 1) {
    if (t < s) red[t] += red[t + s];
    __syncthreads();
  }
  if (t == 0) psum[raw] = red[0];
}

// ---------------- finalize: reduce 2048 partials + vq loss ----------------
__global__ __launch_bounds__(256) void k_fin(
    const float* __restrict__ acc, const float* __restrict__ psum,
    float* __restrict__ out) {
  int t = threadIdx.x;
  float s = 0.f;
  for (int i = t; i < 2048; i += 256) s += psum[i];
  __shared__ float red[256];
  red[t] = s; __syncthreads();
  #pragma unroll
  for (int k = 128; k > 0; k >>= 1) {
    if (t < k) red[t] += red[t + k];
    __syncthreads();
  }
  if (t == 0) {
    float eq  = 1.25f * acc[0] / 4194304.0f;
    float rec = red[0];
    out[0] = eq + rec;
    out[1] = eq;
    out[2] = rec;
  }
}

extern "C" void kernel_launch(void* const* d_in, const int* in_sizes, int n_in,
                              void* d_out, int out_size, void* d_ws, size_t ws_size,
                              hipStream_t stream) {
  (void)in_sizes; (void)n_in; (void)out_size; (void)ws_size;
  const float* x   = (const float*)d_in[0];
  const float* ew1 = (const float*)d_in[1];
  const float* eb1 = (const float*)d_in[2];
  const float* ew2 = (const float*)d_in[3];
  const float* eb2 = (const float*)d_in[4];
  const float* ew3 = (const float*)d_in[5];
  const float* eb3 = (const float*)d_in[6];
  const float* cb  = (const float*)d_in[7];
  const float* dw1 = (const float*)d_in[8];
  const float* db1 = (const float*)d_in[9];
  const float* dw2 = (const float*)d_in[10];
  const float* db2 = (const float*)d_in[11];
  const float* dw3 = (const float*)d_in[12];
  const float* db3 = (const float*)d_in[13];
  float* out = (float*)d_out;
  char*  ws  = (char*)d_ws;

  float*  acc  = (float*)(ws + 0);
  float*  c2   = (float*)(ws + 256);
  float*  wc1p = (float*)(ws + 4096);
  u16*    wc3b = (u16*)  (ws + 8192);        // 16 KB: [hl][ks][nf][lane][8]
  u16*    w3f  = (u16*)  (ws + 24576);
  u16*    w2f  = (u16*)  (ws + 36864);
  u16*    wt1f = (u16*)  (ws + 73728);
  u16*    wt2f = (u16*)  (ws + 147456);
  float*  psum = (float*)(ws + 184320);
  u16*    cbf  = (u16*)  (ws + 262144);
  u16*    z1t  = (u16*)  (ws + 1048576);
  u16*    z2h  = (u16*)  (ws + 18874368);    // 8 MB
  u16*    z2l  = (u16*)  (ws + 27262976);    // 8 MB
  u16*    et   = (u16*)  (ws + 54525952);
  u16*    h1t  = (u16*)  (ws + 1048576);
  u16*    h2t  = (u16*)  (ws + 67108864);
  u16*    z3h  = (u16*)  (ws + 134217728);
  u16*    z3l  = (u16*)  (ws + 142606336);
  float*  xp   = (float*)(ws + 150994944);

  hipMemsetAsync(acc, 0, 64, stream);
  k_prep  <<<3694, 256, 0, stream>>>(ew1, ew2, ew3, dw1, dw2, dw3, cb,
                                     wc1p, wc3b, w3f, c2, w2f, wt1f, wt2f, cbf,
                                     x, xp);
  k_conv1 <<<1024, 256, 0, stream>>>(xp, wc1p, eb1, z1t);
  k_conv2 <<<2048, 256, 0, stream>>>(z1t, w2f, eb2, z2h, z2l);
  k_conv3 <<<512,  256, 0, stream>>>(z2h, z2l, wc3b, eb3, z3h, z3l);
  k_vqpf  <<<1024, 256, 0, stream>>>(z3h, z3l, cbf, c2, cb, et, acc);
  k_convT1<<<1024, 256, 0, stream>>>(et, wt1f, db1, h1t);
  k_convT2<<<1024, 256, 0, stream>>>(h1t, wt2f, db2, h2t);
  k_convT3<<<2048, 256, 0, stream>>>(h2t, w3f, db3, x, out + 3, psum);
  k_fin   <<<1,    256, 0, stream>>>(acc, psum, out);
}

// Round 9
// 264.047 us; speedup vs baseline: 1.0352x; 1.0352x over previous
//
#include <hip/hip_runtime.h>

#define DEV __device__ __forceinline__
typedef unsigned short u16;
typedef __bf16 bf16x8 __attribute__((ext_vector_type(8)));
typedef float f32x4 __attribute__((ext_vector_type(4)));

DEV u16 f2bf(float f) {                      // RNE f32 -> bf16
  unsigned u = __float_as_uint(f);
  u += 0x7FFF + ((u >> 16) & 1);
  return (u16)(u >> 16);
}
DEV float bflo(unsigned u) { return __uint_as_float(u << 16); }          // low u16 -> f32
DEV float bfhi(unsigned u) { return __uint_as_float(u & 0xFFFF0000u); }  // high u16 -> f32

// ---------------- geometry ----------------
// x    [64,3,125,125] fp32
// xp   [64,3,129,128] fp32 zero-padded
// z1t  [64,63,64,32]  bf16
// z3h/z3l [65536][64] bf16 pixel-major hi/lo (conv3 output; z = hi + lo)
// e_t  [64,32,32,64]  bf16  pixel-major
// h1t  [64,64,64,64]  bf16  pixel-major
// h2t  [64,128,128,32] bf16 pixel-major
// xr   [64,3,125,125] fp32
// acc[0] = vq loss sum (atomic from k_vqpf); psum = per-block recon partials

// ---------------- prep + pad fused ----------------
// blocks [0,598): weight/codebook prep. blocks [598,3694): pad x -> xp.
__global__ __launch_bounds__(256) void k_prep(
    const float* __restrict__ ew1, const float* __restrict__ ew2,
    const float* __restrict__ ew3, const float* __restrict__ dw1,
    const float* __restrict__ dw2, const float* __restrict__ dw3,
    const float* __restrict__ cb,
    float* __restrict__ wc1p, u16* __restrict__ wc3b,
    u16* __restrict__ w3f, float* __restrict__ c2,
    u16* __restrict__ w2f, u16* __restrict__ wt1f, u16* __restrict__ wt2f,
    u16* __restrict__ cbf,
    const float* __restrict__ x, float* __restrict__ xp) {
  if (blockIdx.x >= 598) {                 // ---- pad part ----
    int idx = (blockIdx.x - 598) * 256 + threadIdx.x;   // 792576 threads
    int c4 = idx & 31;
    int r  = (idx >> 5) % 129;
    int cbp = (idx >> 5) / 129;
    int ih = r - 1;
    float4 v = make_float4(0.f, 0.f, 0.f, 0.f);
    if ((unsigned)ih < 125u) {
      const float* rp = x + (cbp * 125 + ih) * 125;
      int iw0 = c4 * 4 - 1;
      if (iw0 >= 0)        v.x = rp[iw0];
      if (iw0 + 1 < 125)   v.y = rp[iw0 + 1];
      if (iw0 + 2 < 125)   v.z = rp[iw0 + 2];
      if (iw0 + 3 < 125)   v.w = rp[iw0 + 3];
    }
    *(float4*)(xp + (cbp * 129 + r) * 128 + c4 * 4) = v;
    return;
  }
  int i = blockIdx.x * 256 + threadIdx.x;
  if (i < 864) {
    int cl = i & 7; int t = i >> 3; int tap = t % 9; t /= 9; int ci = t % 3; int cog = t / 3;
    wc1p[i] = ew1[((cog * 8 + cl) * 3 + ci) * 9 + tap];
  } else if (i < 9056) {
    int j = i - 864;                        // wc3b: [hl][ks][nf][lane][8], 8192
    int jj = j & 7; int lane = (j >> 3) & 63; int nf = (j >> 9) & 3; int ks = (j >> 11) & 1; int hl = j >> 12;
    int co = (nf << 4) + (lane & 15);
    int ci = (ks << 5) + ((lane >> 4) << 3) + jj;
    float v = ew3[co * 64 + ci];
    u16 hi = f2bf(v);
    wc3b[j] = hl ? f2bf(v - __uint_as_float((unsigned)hi << 16)) : hi;
  } else if (i < 13152) {
    int j = i - 9056;                       // w3f: [hl][tp][lane][8]
    int jj = j & 7; int lane = (j >> 3) & 63; int tp = (j >> 9) & 3; int hl = j >> 11;
    int kh = tp >> 1, kw = tp & 1;
    int ci = ((lane >> 4) << 3) + jj; int co = lane & 15;
    float wv = (co < 3) ? dw3[((ci * 3 + co) * 2 + kh) * 2 + kw] : 0.f;
    u16 hi = f2bf(wv);
    if (hl == 0) w3f[j] = hi;
    else         w3f[j] = f2bf(wv - __uint_as_float((unsigned)hi << 16));
  } else if (i < 13664) {
    int k = i - 13152;
    const float4* c4 = (const float4*)(cb + (k << 6));
    float s = 0.f;
    #pragma unroll
    for (int q = 0; q < 16; ++q) { float4 v = c4[q]; s += v.x*v.x + v.y*v.y + v.z*v.z + v.w*v.w; }
    c2[k] = s;
  } else if (i < 32096) {
    int j = i - 13664;                      // w2f: [kt][nf][lane][8]
    int jj = j & 7; int lane = (j >> 3) & 63; int nf = (j >> 9) & 3; int kt = j >> 11;
    int kh = kt / 3, kw = kt % 3;
    int ci = ((lane >> 4) << 3) + jj; int co = (nf << 4) + (lane & 15);
    w2f[j] = f2bf(ew2[((co * 32 + ci) * 3 + kh) * 3 + kw]);
  } else if (i < 68960) {
    int j = i - 32096;                      // wt1f: [kt][s][nf][lane][8]
    int jj = j & 7; int lane = (j >> 3) & 63; int nf = (j >> 9) & 3; int s = (j >> 11) & 1; int kt = j >> 12;
    int kh = kt / 3, kw = kt % 3;
    int ci = (s << 5) + ((lane >> 4) << 3) + jj; int co = (nf << 4) + (lane & 15);
    wt1f[j] = f2bf(dw1[((ci * 64 + co) * 3 + kh) * 3 + kw]);
  } else if (i < 87392) {
    int j = i - 68960;                      // wt2f: [kt][s][nf][lane][8]
    int jj = j & 7; int lane = (j >> 3) & 63; int nf = (j >> 9) & 1; int s = (j >> 10) & 1; int kt = j >> 11;
    int kh = kt / 3, kw = kt % 3;
    int ci = (s << 5) + ((lane >> 4) << 3) + jj; int co = (nf << 4) + (lane & 15);
    wt2f[j] = f2bf(dw2[((ci * 32 + co) * 3 + kh) * 3 + kw]);
  } else if (i < 152928) {
    int j = i - 87392;                      // cbf: [hl][ks][nt][lane][8]
    int jj = j & 7; int lane = (j >> 3) & 63; int nt = (j >> 9) & 31; int ks = (j >> 14) & 1; int hl = j >> 15;
    int ci = (ks << 5) + ((lane >> 4) << 3) + jj;
    int code = (nt << 4) + (lane & 15);
    float v = cb[(code << 6) + ci];
    u16 hi = f2bf(v);
    cbf[j] = hl ? f2bf(v - __uint_as_float((unsigned)hi << 16)) : hi;
  }
}

// ---------------- conv1: padded input, all-co blocks, LDS wide stores ----------------
__global__ __launch_bounds__(256) void k_conv1(
    const float* __restrict__ xp, const float* __restrict__ wp,
    const float* __restrict__ bias, u16* __restrict__ z1t) {
  __shared__ u16 st[256 * 34];
  int t = threadIdx.x;
  int slab = blockIdx.x & 15, b = blockIdx.x >> 4;   // grid 1024
  int tx = t & 15, ty = (t >> 4) & 3, cg = t >> 6;
  int oh = slab * 4 + ty;
  int co0 = cg * 8;
  const float* wcg = wp + cg * 216;
  float acc[8][4];
  #pragma unroll
  for (int c = 0; c < 8; ++c) {
    float bv = bias[co0 + c];
    #pragma unroll
    for (int s = 0; s < 4; ++s) acc[c][s] = bv;
  }
  #pragma unroll
  for (int ci = 0; ci < 3; ++ci) {
    #pragma unroll
    for (int kh = 0; kh < 3; ++kh) {
      const float* rp = xp + ((b * 3 + ci) * 129 + (2 * oh + kh)) * 128 + 8 * tx;
      float4 qa = *(const float4*)rp;
      float4 qb = *(const float4*)(rp + 4);
      float v8 = rp[8];
      float v[9] = {qa.x, qa.y, qa.z, qa.w, qb.x, qb.y, qb.z, qb.w, v8};
      #pragma unroll
      for (int kw = 0; kw < 3; ++kw) {
        const float* wq = wcg + (ci * 9 + kh * 3 + kw) * 8;
        float4 wa = *(const float4*)wq;
        float4 wb = *(const float4*)(wq + 4);
        float w8[8] = {wa.x, wa.y, wa.z, wa.w, wb.x, wb.y, wb.z, wb.w};
        #pragma unroll
        for (int s = 0; s < 4; ++s) {
          float in = v[2 * s + kw];
          #pragma unroll
          for (int c = 0; c < 8; ++c) acc[c][s] = fmaf(in, w8[c], acc[c][s]);
        }
      }
    }
  }
  #pragma unroll
  for (int s = 0; s < 4; ++s) {
    bool wok = (tx * 4 + s) < 63;
    unsigned p0 = 0, p1 = 0, p2 = 0, p3 = 0;
    if (wok) {
      p0 = f2bf(fmaxf(acc[0][s], 0.f)) | ((unsigned)f2bf(fmaxf(acc[1][s], 0.f)) << 16);
      p1 = f2bf(fmaxf(acc[2][s], 0.f)) | ((unsigned)f2bf(fmaxf(acc[3][s], 0.f)) << 16);
      p2 = f2bf(fmaxf(acc[4][s], 0.f)) | ((unsigned)f2bf(fmaxf(acc[5][s], 0.f)) << 16);
      p3 = f2bf(fmaxf(acc[6][s], 0.f)) | ((unsigned)f2bf(fmaxf(acc[7][s], 0.f)) << 16);
    }
    int lpix = tx * 16 + ty * 4 + s;
    *(uint4*)&st[lpix * 34 + co0] = make_uint4(p0, p1, p2, p3);
  }
  __syncthreads();
  {
    int p = t;
    int ow = (p >> 4) * 4 + (p & 3);
    int ohl = (p >> 2) & 3;
    int oho = slab * 4 + ohl;
    if (oho < 63) {
      const u16* lp = &st[p * 34];
      uint4 a0 = *(const uint4*)(lp);
      uint4 a1 = *(const uint4*)(lp + 8);
      uint4 a2 = *(const uint4*)(lp + 16);
      uint4 a3 = *(const uint4*)(lp + 24);
      uint4* gp = (uint4*)(z1t + ((b * 63 + oho) * 64 + ow) * 32);
      gp[0] = a0; gp[1] = a1; gp[2] = a2; gp[3] = a3;
    }
  }
}

// ---------------- conv2+conv3 fused: stencil MFMA -> LDS hi/lo -> 1x1 MFMA -> z3h/z3l ----------------
// conv3 is 1x1 (per-pixel); conv2 block produces all 64 ch for its 32 px, so conv3
// runs from LDS. Eliminates z2h/z2l HBM round-trip + one launch. Bit-identical math.
__global__ __launch_bounds__(256) void k_conv23(
    const u16* __restrict__ z1t, const u16* __restrict__ wf,
    const float* __restrict__ b2, const u16* __restrict__ wcb,
    const float* __restrict__ b3,
    u16* __restrict__ z3h, u16* __restrict__ z3l) {
  __shared__ u16 sh[32 * 72];
  __shared__ u16 sl[32 * 72];
  __shared__ u16 lh[32 * 72];
  __shared__ u16 ll[32 * 72];
  int t = threadIdx.x;
  int lane = t & 63, wv = t >> 6;
  int n = lane & 15, q = lane >> 4;
  int raw = blockIdx.x;                           // grid 2048 = 8*256
  int wg = ((raw & 7) << 8) + (raw >> 3);         // bijective XCD swizzle
  int oh = wg & 31, b = wg >> 5;
  int xt = wv & 1, ch = wv >> 1;
  int xA = xt * 16 + n;
  f32x4 acc[2] = {{0,0,0,0},{0,0,0,0}};
  #pragma unroll
  for (int kh = 0; kh < 3; ++kh) {
    int ih = 2 * oh - 1 + kh;
    bool yok = (unsigned)ih < 63u;
    #pragma unroll
    for (int kw = 0; kw < 3; ++kw) {
      int iw = 2 * xA - 1 + kw;
      bool ok = yok && (iw >= 0);
      bf16x8 a = {};
      if (ok) a = *(const bf16x8*)(z1t + ((b * 63 + ih) * 64 + iw) * 32 + q * 8);
      int kt = kh * 3 + kw;
      const u16* wb = wf + ((kt << 2) + (ch << 1)) * 512 + lane * 8;
      bf16x8 b0 = *(const bf16x8*)wb;
      bf16x8 b1 = *(const bf16x8*)(wb + 512);
      acc[0] = __builtin_amdgcn_mfma_f32_16x16x32_bf16(a, b0, acc[0], 0, 0, 0);
      acc[1] = __builtin_amdgcn_mfma_f32_16x16x32_bf16(a, b1, acc[1], 0, 0, 0);
    }
  }
  #pragma unroll
  for (int j = 0; j < 2; ++j) {
    int co = ((ch << 1) + j) * 16 + n;
    float bv = b2[co];
    #pragma unroll
    for (int r = 0; r < 4; ++r) {
      int ow = xt * 16 + q * 4 + r;
      float v = fmaxf(acc[j][r] + bv, 0.f);
      u16 h = f2bf(v);
      u16 l = f2bf(v - __uint_as_float((unsigned)h << 16));
      sh[ow * 72 + co] = h;
      sl[ow * 72 + co] = l;
    }
  }
  __syncthreads();
  // ---- conv3 (1x1) from LDS: wave wv = nf (16 co), 2 mt of 16 px ----
  {
    const u16* wb = wcb + (wv << 9) + lane * 8;
    bf16x8 Bh0 = *(const bf16x8*)wb;
    bf16x8 Bh1 = *(const bf16x8*)(wb + 2048);
    bf16x8 Bl0 = *(const bf16x8*)(wb + 4096);
    bf16x8 Bl1 = *(const bf16x8*)(wb + 6144);
    int co = (wv << 4) + n;
    float bv = b3[co];
    #pragma unroll
    for (int mti = 0; mti < 2; ++mti) {
      int base = (mti * 16 + n) * 72 + q * 8;
      bf16x8 Ah0 = *(const bf16x8*)&sh[base];
      bf16x8 Ah1 = *(const bf16x8*)&sh[base + 32];
      bf16x8 Al0 = *(const bf16x8*)&sl[base];
      bf16x8 Al1 = *(const bf16x8*)&sl[base + 32];
      f32x4 a = {0.f, 0.f, 0.f, 0.f};
      a = __builtin_amdgcn_mfma_f32_16x16x32_bf16(Ah0, Bh0, a, 0, 0, 0);
      a = __builtin_amdgcn_mfma_f32_16x16x32_bf16(Ah1, Bh1, a, 0, 0, 0);
      a = __builtin_amdgcn_mfma_f32_16x16x32_bf16(Al0, Bh0, a, 0, 0, 0);
      a = __builtin_amdgcn_mfma_f32_16x16x32_bf16(Al1, Bh1, a, 0, 0, 0);
      a = __builtin_amdgcn_mfma_f32_16x16x32_bf16(Ah0, Bl0, a, 0, 0, 0);
      a = __builtin_amdgcn_mfma_f32_16x16x32_bf16(Ah1, Bl1, a, 0, 0, 0);
      int pxl0 = mti * 16 + q * 4;
      #pragma unroll
      for (int r = 0; r < 4; ++r) {
        float v = a[r] + bv;
        u16 h = f2bf(v);
        u16 l = f2bf(v - __uint_as_float((unsigned)h << 16));
        lh[(pxl0 + r) * 72 + co] = h;
        ll[(pxl0 + r) * 72 + co] = l;
      }
    }
  }
  __syncthreads();
  {
    int px = t >> 3, sg = t & 7;
    uint4 hv = *(const uint4*)&lh[px * 72 + sg * 8];
    uint4 lv = *(const uint4*)&ll[px * 72 + sg * 8];
    long gp = ((long)(b * 1024 + oh * 32 + px) << 6) + sg * 8;
    *(uint4*)(z3h + gp) = hv;
    *(uint4*)(z3l + gp) = lv;
  }
}

// ---------------- VQ fused: argmin (MFMA hi/lo, 4-wave code split) + gather/loss/et ----------------
// grid 1024, 64 px/block, 4 mt/wave, rolled nt loop + register prefetch (r8 config).
__global__ __launch_bounds__(256) void k_vqpf(
    const u16* __restrict__ z3h, const u16* __restrict__ z3l,
    const u16* __restrict__ cbf, const float* __restrict__ c2v,
    const float* __restrict__ cb,
    u16* __restrict__ et, float* __restrict__ acc) {
  int t = threadIdx.x;
  int lane = t & 63, wv = t >> 6;
  int n = lane & 15, q = lane >> 4;
  int p0 = blockIdx.x * 64;
  bf16x8 Ah[4][2], Al[4][2];
  #pragma unroll
  for (int mt = 0; mt < 4; ++mt) {
    const u16* ap = z3h + (p0 + mt * 16 + n) * 64 + q * 8;
    const u16* al = z3l + (p0 + mt * 16 + n) * 64 + q * 8;
    Ah[mt][0] = *(const bf16x8*)ap;  Ah[mt][1] = *(const bf16x8*)(ap + 32);
    Al[mt][0] = *(const bf16x8*)al;  Al[mt][1] = *(const bf16x8*)(al + 32);
  }
  float bs[4][4]; int bix[4][4];
  #pragma unroll
  for (int mt = 0; mt < 4; ++mt)
    #pragma unroll
    for (int r = 0; r < 4; ++r) { bs[mt][r] = 3.4e38f; bix[mt][r] = 0; }
  const u16* bp = cbf + lane * 8;
  int ntb = wv * 8;
  bf16x8 nBh0 = *(const bf16x8*)(bp + (ntb << 9));
  bf16x8 nBh1 = *(const bf16x8*)(bp + ((32 + ntb) << 9));
  bf16x8 nBl0 = *(const bf16x8*)(bp + ((64 + ntb) << 9));
  bf16x8 nBl1 = *(const bf16x8*)(bp + ((96 + ntb) << 9));
  for (int nt0 = 0; nt0 < 8; ++nt0) {
    int nt = ntb + nt0;
    bf16x8 Bh0 = nBh0, Bh1 = nBh1, Bl0 = nBl0, Bl1 = nBl1;
    int ntn = nt + ((nt0 < 7) ? 1 : 0);       // last iter reloads same (L2-hot, harmless)
    nBh0 = *(const bf16x8*)(bp + (ntn << 9));
    nBh1 = *(const bf16x8*)(bp + ((32 + ntn) << 9));
    nBl0 = *(const bf16x8*)(bp + ((64 + ntn) << 9));
    nBl1 = *(const bf16x8*)(bp + ((96 + ntn) << 9));
    float c2 = c2v[(nt << 4) + n];
    #pragma unroll
    for (int mt = 0; mt < 4; ++mt) {
      f32x4 a = {0.f, 0.f, 0.f, 0.f};
      a = __builtin_amdgcn_mfma_f32_16x16x32_bf16(Ah[mt][0], Bh0, a, 0, 0, 0);
      a = __builtin_amdgcn_mfma_f32_16x16x32_bf16(Ah[mt][1], Bh1, a, 0, 0, 0);
      a = __builtin_amdgcn_mfma_f32_16x16x32_bf16(Al[mt][0], Bh0, a, 0, 0, 0);
      a = __builtin_amdgcn_mfma_f32_16x16x32_bf16(Al[mt][1], Bh1, a, 0, 0, 0);
      a = __builtin_amdgcn_mfma_f32_16x16x32_bf16(Ah[mt][0], Bl0, a, 0, 0, 0);
      a = __builtin_amdgcn_mfma_f32_16x16x32_bf16(Ah[mt][1], Bl1, a, 0, 0, 0);
      int idx = (nt << 4) + n;
      #pragma unroll
      for (int r = 0; r < 4; ++r) {
        float sc = fmaf(-2.f, a[r], c2);
        if (sc < bs[mt][r]) { bs[mt][r] = sc; bix[mt][r] = idx; }
      }
    }
  }
  #pragma unroll
  for (int off = 8; off > 0; off >>= 1) {
    #pragma unroll
    for (int mt = 0; mt < 4; ++mt)
      #pragma unroll
      for (int r = 0; r < 4; ++r) {
        float os = __shfl_xor(bs[mt][r], off, 16);
        int oi = __shfl_xor(bix[mt][r], off, 16);
        if (os < bs[mt][r] || (os == bs[mt][r] && oi < bix[mt][r])) {
          bs[mt][r] = os; bix[mt][r] = oi;
        }
      }
  }
  __shared__ float ls[4][64];
  __shared__ int   li[4][64];
  __shared__ int   lfin[64];
  if (n == 0) {
    #pragma unroll
    for (int mt = 0; mt < 4; ++mt)
      #pragma unroll
      for (int r = 0; r < 4; ++r) {
        int px = mt * 16 + q * 4 + r;
        ls[wv][px] = bs[mt][r];
        li[wv][px] = bix[mt][r];
      }
  }
  __syncthreads();
  if (t < 64) {
    float best = ls[0][t]; int bi = li[0][t];
    #pragma unroll
    for (int w = 1; w < 4; ++w) {
      float s = ls[w][t]; int ii = li[w][t];
      if (s < best || (s == best && ii < bi)) { best = s; bi = ii; }
    }
    lfin[t] = bi;
  }
  __syncthreads();
  // ---- phase 2: gather codebook, write et, e-q loss (z from coalesced hi/lo) ----
  int pxl = t >> 2, ciq = t & 3;            // 64 px x 4 channel-quads (16 ch each)
  int ng = p0 + pxl;
  int bi = lfin[pxl];
  const u16* zh = z3h + ((long)ng << 6) + (ciq << 4);
  const u16* zl = z3l + ((long)ng << 6) + (ciq << 4);
  uint4 h0v = *(const uint4*)zh, h1v = *(const uint4*)(zh + 8);
  uint4 l0v = *(const uint4*)zl, l1v = *(const uint4*)(zl + 8);
  unsigned hw_[8] = {h0v.x, h0v.y, h0v.z, h0v.w, h1v.x, h1v.y, h1v.z, h1v.w};
  unsigned lw_[8] = {l0v.x, l0v.y, l0v.z, l0v.w, l1v.x, l1v.y, l1v.z, l1v.w};
  const float4* cq = (const float4*)(cb + (bi << 6) + (ciq << 4));
  float lsum = 0.f;
  unsigned pk[8];
  #pragma unroll
  for (int i = 0; i < 4; ++i) {
    float4 c = cq[i];
    float z0 = bflo(hw_[2 * i])     + bflo(lw_[2 * i]);
    float z1 = bfhi(hw_[2 * i])     + bfhi(lw_[2 * i]);
    float z2 = bflo(hw_[2 * i + 1]) + bflo(lw_[2 * i + 1]);
    float z3 = bfhi(hw_[2 * i + 1]) + bfhi(lw_[2 * i + 1]);
    float df;
    df = c.x - z0; lsum = fmaf(df, df, lsum);
    df = c.y - z1; lsum = fmaf(df, df, lsum);
    df = c.z - z2; lsum = fmaf(df, df, lsum);
    df = c.w - z3; lsum = fmaf(df, df, lsum);
    pk[2 * i]     = f2bf(c.x) | ((unsigned)f2bf(c.y) << 16);
    pk[2 * i + 1] = f2bf(c.z) | ((unsigned)f2bf(c.w) << 16);
  }
  uint4* ep = (uint4*)(et + ((long)ng << 6) + (ciq << 4));
  ep[0] = make_uint4(pk[0], pk[1], pk[2], pk[3]);
  ep[1] = make_uint4(pk[4], pk[5], pk[6], pk[7]);
  __shared__ float red[256];
  red[t] = lsum; __syncthreads();
  #pragma unroll
  for (int s = 128; s > 0; s >>= 1) {
    if (t < s) red[t] += red[t + s];
    __syncthreads();
  }
  if (t == 0) atomicAdd(acc + 0, red[0]);
}

// ---------------- convT1: cog-split, LDS weights, XCD-swizzled ----------------
__global__ __launch_bounds__(256) void k_convT1(
    const u16* __restrict__ et, const u16* __restrict__ wf,
    const float* __restrict__ bias, u16* __restrict__ h1t) {
  __shared__ u16 wl[36 * 512];      // 36864 B
  __shared__ u16 st[4][64 * 34];    // 17408 B
  int t = threadIdx.x;
  int lane = t & 63, wv = t >> 6;
  int yw = wv & 1, xt = wv >> 1;
  int raw = blockIdx.x;                          // grid 1024 = 8*128
  int wg = ((raw & 7) << 7) + (raw >> 3);        // bijective XCD swizzle
  int cog = wg & 1;
  int yg = (wg >> 1) & 7;
  int b = wg >> 4;
  {
    const uint4* gw = (const uint4*)wf;
    uint4* lw = (uint4*)wl;
    #pragma unroll
    for (int k = 0; k < 9; ++k) {
      int i = t + 256 * k;
      int slot = i >> 6, within = i & 63;
      int kt = slot >> 2, j = (slot >> 1) & 1, ks = slot & 1;
      int goff = (kt << 12) + (((ks << 2) + (cog << 1) + j) << 9);
      lw[i] = gw[(goff >> 3) + within];
    }
  }
  int n = lane & 15, q = lane >> 4;
  int m = xt * 16 + n;
  __syncthreads();
  for (int iter = 0; iter < 2; ++iter) {
    int y = yg * 4 + iter * 2 + yw;
    const u16* base0 = et + (((b * 32 + y) * 32) << 6) + q * 8;
    bf16x8 P00a, P00b, P01a = {}, P01b = {}, P10a = {}, P10b = {}, P11a = {}, P11b = {};
    { const u16* p = base0 + (m << 6); P00a = *(const bf16x8*)p; P00b = *(const bf16x8*)(p + 32); }
    if (m + 1 < 32) { const u16* p = base0 + ((m + 1) << 6); P01a = *(const bf16x8*)p; P01b = *(const bf16x8*)(p + 32); }
    if (y + 1 < 32) {
      const u16* base1 = base0 + (32 << 6);
      { const u16* p = base1 + (m << 6); P10a = *(const bf16x8*)p; P10b = *(const bf16x8*)(p + 32); }
      if (m + 1 < 32) { const u16* p = base1 + ((m + 1) << 6); P11a = *(const bf16x8*)p; P11b = *(const bf16x8*)(p + 32); }
    }
    f32x4 accE[2][2] = {};  // [j][pwi]
    f32x4 accO[2][2] = {};
    #pragma unroll
    for (int kw = 0; kw < 3; ++kw) {
      int pwi = (kw == 1) ? 0 : 1;
      bf16x8 A0a = (kw == 0) ? P01a : P00a;
      bf16x8 A0b = (kw == 0) ? P01b : P00b;
      bf16x8 A1a = (kw == 0) ? P11a : P10a;
      bf16x8 A1b = (kw == 0) ? P11b : P10b;
      #pragma unroll
      for (int j = 0; j < 2; ++j) {
        const u16* wE  = wl + ((((3 + kw) << 2) + (j << 1)) << 9) + lane * 8;
        const u16* wO0 = wl + (((kw << 2) + (j << 1)) << 9) + lane * 8;
        const u16* wO2 = wl + ((((6 + kw) << 2) + (j << 1)) << 9) + lane * 8;
        bf16x8 bE0 = *(const bf16x8*)wE;
        bf16x8 bE1 = *(const bf16x8*)(wE + 512);
        accE[j][pwi] = __builtin_amdgcn_mfma_f32_16x16x32_bf16(A0a, bE0, accE[j][pwi], 0, 0, 0);
        accE[j][pwi] = __builtin_amdgcn_mfma_f32_16x16x32_bf16(A0b, bE1, accE[j][pwi], 0, 0, 0);
        bf16x8 bO00 = *(const bf16x8*)wO0;
        bf16x8 bO01 = *(const bf16x8*)(wO0 + 512);
        accO[j][pwi] = __builtin_amdgcn_mfma_f32_16x16x32_bf16(A1a, bO00, accO[j][pwi], 0, 0, 0);
        accO[j][pwi] = __builtin_amdgcn_mfma_f32_16x16x32_bf16(A1b, bO01, accO[j][pwi], 0, 0, 0);
        bf16x8 bO20 = *(const bf16x8*)wO2;
        bf16x8 bO21 = *(const bf16x8*)(wO2 + 512);
        accO[j][pwi] = __builtin_amdgcn_mfma_f32_16x16x32_bf16(A0a, bO20, accO[j][pwi], 0, 0, 0);
        accO[j][pwi] = __builtin_amdgcn_mfma_f32_16x16x32_bf16(A0b, bO21, accO[j][pwi], 0, 0, 0);
      }
    }
    #pragma unroll
    for (int j = 0; j < 2; ++j) {
      int col = j * 16 + n;
      float bv = bias[cog * 32 + col];
      #pragma unroll
      for (int pw = 0; pw < 2; ++pw)
        #pragma unroll
        for (int r = 0; r < 4; ++r) {
          int ow = 2 * (xt * 16 + q * 4 + r) + pw;
          st[yw * 2 + 0][ow * 34 + col] = f2bf(fmaxf(accE[j][pw][r] + bv, 0.f));
          st[yw * 2 + 1][ow * 34 + col] = f2bf(fmaxf(accO[j][pw][r] + bv, 0.f));
        }
    }
    __syncthreads();
    {
      int row = t >> 6, ow = t & 63;   // 4 rows x 64 ow
      const u16* lp = &st[row][ow * 34];
      uint4* gp = (uint4*)(h1t + (((b * 64 + yg * 8 + iter * 4 + row) * 64 + ow) << 6) + cog * 32);
      gp[0] = *(const uint4*)(lp);
      gp[1] = *(const uint4*)(lp + 8);
      gp[2] = *(const uint4*)(lp + 16);
      gp[3] = *(const uint4*)(lp + 24);
    }
    __syncthreads();
  }
}

// ---------------- convT2: LDS weights, 4 y-pairs/block loop, XCD-swizzled ----------------
__global__ __launch_bounds__(256) void k_convT2(
    const u16* __restrict__ h1t, const u16* __restrict__ wf,
    const float* __restrict__ bias, u16* __restrict__ h2t) {
  __shared__ u16 wl[18432];         // 36864 B
  __shared__ u16 st[2][128 * 34];   // 17408 B
  int t = threadIdx.x;
  int lane = t & 63, xt = t >> 6;
  int n = lane & 15, q = lane >> 4;
  int raw = blockIdx.x;                          // grid 1024 = 8*128
  int wg = ((raw & 7) << 7) + (raw >> 3);        // bijective XCD swizzle
  int yg = wg & 15, b = wg >> 4;
  {
    const uint4* gw = (const uint4*)wf;
    uint4* lw = (uint4*)wl;
    #pragma unroll
    for (int k = 0; k < 9; ++k) lw[t + 256 * k] = gw[t + 256 * k];
  }
  int m = xt * 16 + n;
  __syncthreads();
  for (int yp = 0; yp < 4; ++yp) {
    int y = yg * 4 + yp;
    const u16* base0 = h1t + (((b * 64 + y) * 64) << 6) + q * 8;
    bf16x8 P00a, P00b, P01a = {}, P01b = {}, P10a = {}, P10b = {}, P11a = {}, P11b = {};
    { const u16* p = base0 + (m << 6); P00a = *(const bf16x8*)p; P00b = *(const bf16x8*)(p + 32); }
    if (m + 1 < 64) { const u16* p = base0 + ((m + 1) << 6); P01a = *(const bf16x8*)p; P01b = *(const bf16x8*)(p + 32); }
    if (y + 1 < 64) {
      const u16* base1 = base0 + (64 << 6);
      { const u16* p = base1 + (m << 6); P10a = *(const bf16x8*)p; P10b = *(const bf16x8*)(p + 32); }
      if (m + 1 < 64) { const u16* p = base1 + ((m + 1) << 6); P11a = *(const bf16x8*)p; P11b = *(const bf16x8*)(p + 32); }
    }
    f32x4 accE[2][2] = {};  // [nf][pwi]
    f32x4 accO[2][2] = {};
    #pragma unroll
    for (int kw = 0; kw < 3; ++kw) {
      int pwi = (kw == 1) ? 0 : 1;
      bf16x8 A0a = (kw == 0) ? P01a : P00a;
      bf16x8 A0b = (kw == 0) ? P01b : P00b;
      bf16x8 A1a = (kw == 0) ? P11a : P10a;
      bf16x8 A1b = (kw == 0) ? P11b : P10b;
      const u16* wbE = wl + ((3 + kw) << 11) + lane * 8;
      const u16* wbO0 = wl + (kw << 11) + lane * 8;
      const u16* wbO2 = wl + ((6 + kw) << 11) + lane * 8;
      #pragma unroll
      for (int nf = 0; nf < 2; ++nf) {
        bf16x8 bE0 = *(const bf16x8*)(wbE + nf * 512);
        bf16x8 bE1 = *(const bf16x8*)(wbE + (2 + nf) * 512);
        accE[nf][pwi] = __builtin_amdgcn_mfma_f32_16x16x32_bf16(A0a, bE0, accE[nf][pwi], 0, 0, 0);
        accE[nf][pwi] = __builtin_amdgcn_mfma_f32_16x16x32_bf16(A0b, bE1, accE[nf][pwi], 0, 0, 0);
        bf16x8 bO00 = *(const bf16x8*)(wbO0 + nf * 512);
        bf16x8 bO01 = *(const bf16x8*)(wbO0 + (2 + nf) * 512);
        accO[nf][pwi] = __builtin_amdgcn_mfma_f32_16x16x32_bf16(A1a, bO00, accO[nf][pwi], 0, 0, 0);
        accO[nf][pwi] = __builtin_amdgcn_mfma_f32_16x16x32_bf16(A1b, bO01, accO[nf][pwi], 0, 0, 0);
        bf16x8 bO20 = *(const bf16x8*)(wbO2 + nf * 512);
        bf16x8 bO21 = *(const bf16x8*)(wbO2 + (2 + nf) * 512);
        accO[nf][pwi] = __builtin_amdgcn_mfma_f32_16x16x32_bf16(A0a, bO20, accO[nf][pwi], 0, 0, 0);
        accO[nf][pwi] = __builtin_amdgcn_mfma_f32_16x16x32_bf16(A0b, bO21, accO[nf][pwi], 0, 0, 0);
      }
    }
    #pragma unroll
    for (int nf = 0; nf < 2; ++nf) {
      int co = nf * 16 + n;
      float bv = bias[co];
      #pragma unroll
      for (int pw = 0; pw < 2; ++pw)
        #pragma unroll
        for (int r = 0; r < 4; ++r) {
          int ow = 2 * (xt * 16 + q * 4 + r) + pw;
          st[0][ow * 34 + co] = f2bf(fmaxf(accE[nf][pw][r] + bv, 0.f));
          st[1][ow * 34 + co] = f2bf(fmaxf(accO[nf][pw][r] + bv, 0.f));
        }
    }
    __syncthreads();
    {
      int ow = t >> 1, sg = t & 1;
      #pragma unroll
      for (int l = 0; l < 2; ++l) {
        const u16* lp = &st[l][ow * 34 + sg * 16];
        unsigned w0 = *(const unsigned*)(lp + 0), w1 = *(const unsigned*)(lp + 2);
        unsigned w2 = *(const unsigned*)(lp + 4), w3 = *(const unsigned*)(lp + 6);
        unsigned w4 = *(const unsigned*)(lp + 8), w5 = *(const unsigned*)(lp + 10);
        unsigned w6 = *(const unsigned*)(lp + 12), w7 = *(const unsigned*)(lp + 14);
        uint4* gp = (uint4*)(h2t + ((((b * 128 + yg * 8 + yp * 2 + l) * 128) + ow) << 5) + sg * 16);
        gp[0] = make_uint4(w0, w1, w2, w3);
        gp[1] = make_uint4(w4, w5, w6, w7);
      }
    }
    __syncthreads();
  }
}

// ---------------- convT3 + recon loss: 5-rows-once, 4 indep MFMA chains ----------------
// grid 2048 = 64 b x 32 row-groups, XCD-swizzled. psum partials + k_fin (no fences).
__global__ __launch_bounds__(256) void k_convT3(
    const u16* __restrict__ h2t, const u16* __restrict__ w3f,
    const float* __restrict__ bias, const float* __restrict__ x,
    float* __restrict__ xr, float* __restrict__ psum) {
  int t = threadIdx.x;
  int lane = t & 63, wv = t >> 6;
  int n = lane & 15, q = lane >> 4;
  int raw = blockIdx.x;                          // grid 2048 = 8*256
  int wg = ((raw & 7) << 8) + (raw >> 3);        // bijective XCD swizzle
  int rg = wg & 31, b = wg >> 5;
  int oh0 = rg * 4;
  const u16* wbp = w3f + lane * 8;
  bf16x8 Bh0 = *(const bf16x8*)(wbp);
  bf16x8 Bh1 = *(const bf16x8*)(wbp + 512);
  bf16x8 Bh2 = *(const bf16x8*)(wbp + 1024);
  bf16x8 Bh3 = *(const bf16x8*)(wbp + 1536);
  bf16x8 Bl0 = *(const bf16x8*)(wbp + 2048);
  bf16x8 Bl1 = *(const bf16x8*)(wbp + 2560);
  bf16x8 Bl2 = *(const bf16x8*)(wbp + 3072);
  bf16x8 Bl3 = *(const bf16x8*)(wbp + 3584);
  float bv = (n < 3) ? bias[n] : 0.f;
  float lsum = 0.f;
  if (oh0 <= 121) {
    const u16* rbase = h2t + (((long)b * 128 + (oh0 + 1)) << 12) + q * 8;
    #pragma unroll
    for (int ti = 0; ti < 2; ++ti) {
      int tt = wv + ti * 4;
      int c1 = tt * 16 + n + 1;
      int c2 = c1 + 1;
      bf16x8 A[5][2];
      #pragma unroll
      for (int j = 0; j < 5; ++j) {
        A[j][0] = (bf16x8){}; A[j][1] = (bf16x8){};
        const u16* rp = rbase + ((long)j << 12);
        if (c1 < 128) A[j][0] = *(const bf16x8*)(rp + (c1 << 5));
        if (c2 < 128) A[j][1] = *(const bf16x8*)(rp + (c2 << 5));
      }
      f32x4 ac[4] = {};
      #pragma unroll
      for (int k = 0; k < 4; ++k) {
        ac[k] = __builtin_amdgcn_mfma_f32_16x16x32_bf16(A[k][0],     Bh3, ac[k], 0, 0, 0);
        ac[k] = __builtin_amdgcn_mfma_f32_16x16x32_bf16(A[k][1],     Bh2, ac[k], 0, 0, 0);
        ac[k] = __builtin_amdgcn_mfma_f32_16x16x32_bf16(A[k + 1][0], Bh1, ac[k], 0, 0, 0);
        ac[k] = __builtin_amdgcn_mfma_f32_16x16x32_bf16(A[k + 1][1], Bh0, ac[k], 0, 0, 0);
        ac[k] = __builtin_amdgcn_mfma_f32_16x16x32_bf16(A[k][0],     Bl3, ac[k], 0, 0, 0);
        ac[k] = __builtin_amdgcn_mfma_f32_16x16x32_bf16(A[k][1],     Bl2, ac[k], 0, 0, 0);
        ac[k] = __builtin_amdgcn_mfma_f32_16x16x32_bf16(A[k + 1][0], Bl1, ac[k], 0, 0, 0);
        ac[k] = __builtin_amdgcn_mfma_f32_16x16x32_bf16(A[k + 1][1], Bl0, ac[k], 0, 0, 0);
      }
      if (n < 3) {
        int ow0 = tt * 16 + q * 4;
        #pragma unroll
        for (int k = 0; k < 4; ++k) {
          int oh = oh0 + k;
          int o = b * 46875 + n * 15625 + oh * 125 + ow0;
          if (ow0 + 3 < 125) {
            float4 v = make_float4(ac[k][0] + bv, ac[k][1] + bv, ac[k][2] + bv, ac[k][3] + bv);
            float4 xv = *(const float4*)(x + o);
            *(float4*)(xr + o) = v;
            float d0 = v.x - xv.x, d1 = v.y - xv.y, d2 = v.z - xv.z, d3 = v.w - xv.w;
            lsum += d0 * d0 + d1 * d1 + d2 * d2 + d3 * d3;
          } else {
            #pragma unroll
            for (int r = 0; r < 4; ++r) {
              if (ow0 + r < 125) {
                float v = ac[k][r] + bv;
                xr[o + r] = v;
                float d = v - x[o + r];
                lsum = fmaf(d, d, lsum);
              }
            }
          }
        }
      }
    }
  } else {
    int oh = 124;
    const u16* row1 = h2t + (((long)b * 128 + (oh + 1)) << 12) + q * 8;
    const u16* row2 = row1 + 4096;
    #pragma unroll
    for (int ti = 0; ti < 2; ++ti) {
      int tt = wv + ti * 4;
      int c1 = tt * 16 + n + 1;
      int c2 = c1 + 1;
      bf16x8 a11 = {}, a12 = {}, a21 = {}, a22 = {};
      if (c1 < 128) { a11 = *(const bf16x8*)(row1 + (c1 << 5));
                      a21 = *(const bf16x8*)(row2 + (c1 << 5)); }
      if (c2 < 128) { a12 = *(const bf16x8*)(row1 + (c2 << 5));
                      a22 = *(const bf16x8*)(row2 + (c2 << 5)); }
      f32x4 a = {0.f, 0.f, 0.f, 0.f};
      a = __builtin_amdgcn_mfma_f32_16x16x32_bf16(a11, Bh3, a, 0, 0, 0);
      a = __builtin_amdgcn_mfma_f32_16x16x32_bf16(a12, Bh2, a, 0, 0, 0);
      a = __builtin_amdgcn_mfma_f32_16x16x32_bf16(a21, Bh1, a, 0, 0, 0);
      a = __builtin_amdgcn_mfma_f32_16x16x32_bf16(a22, Bh0, a, 0, 0, 0);
      a = __builtin_amdgcn_mfma_f32_16x16x32_bf16(a11, Bl3, a, 0, 0, 0);
      a = __builtin_amdgcn_mfma_f32_16x16x32_bf16(a12, Bl2, a, 0, 0, 0);
      a = __builtin_amdgcn_mfma_f32_16x16x32_bf16(a21, Bl1, a, 0, 0, 0);
      a = __builtin_amdgcn_mfma_f32_16x16x32_bf16(a22, Bl0, a, 0, 0, 0);
      if (n < 3) {
        int ow0 = tt * 16 + q * 4;
        int o = b * 46875 + n * 15625 + oh * 125 + ow0;
        if (ow0 + 3 < 125) {
          float4 v = make_float4(a[0] + bv, a[1] + bv, a[2] + bv, a[3] + bv);
          float4 xv = *(const float4*)(x + o);
          *(float4*)(xr + o) = v;
          float d0 = v.x - xv.x, d1 = v.y - xv.y, d2 = v.z - xv.z, d3 = v.w - xv.w;
          lsum += d0 * d0 + d1 * d1 + d2 * d2 + d3 * d3;
        } else {
          #pragma unroll
          for (int r = 0; r < 4; ++r) {
            if (ow0 + r < 125) {
              float v = a[r] + bv;
              xr[o + r] = v;
              float d = v - x[o + r];
              lsum = fmaf(d, d, lsum);
            }
          }
        }
      }
    }
  }
  __shared__ float red[256];
  red[t] = lsum; __syncthreads();
  #pragma unroll
  for (int s = 128; s > 0; s >>= 1) {
    if (t < s) red[t] += red[t + s];
    __syncthreads();
  }
  if (t == 0) psum[raw] = red[0];
}

// ---------------- finalize: reduce 2048 partials + vq loss ----------------
__global__ __launch_bounds__(256) void k_fin(
    const float* __restrict__ acc, const float* __restrict__ psum,
    float* __restrict__ out) {
  int t = threadIdx.x;
  float s = 0.f;
  for (int i = t; i < 2048; i += 256) s += psum[i];
  __shared__ float red[256];
  red[t] = s; __syncthreads();
  #pragma unroll
  for (int k = 128; k > 0; k >>= 1) {
    if (t < k) red[t] += red[t + k];
    __syncthreads();
  }
  if (t == 0) {
    float eq  = 1.25f * acc[0] / 4194304.0f;
    float rec = red[0];
    out[0] = eq + rec;
    out[1] = eq;
    out[2] = rec;
  }
}

extern "C" void kernel_launch(void* const* d_in, const int* in_sizes, int n_in,
                              void* d_out, int out_size, void* d_ws, size_t ws_size,
                              hipStream_t stream) {
  (void)in_sizes; (void)n_in; (void)out_size; (void)ws_size;
  const float* x   = (const float*)d_in[0];
  const float* ew1 = (const float*)d_in[1];
  const float* eb1 = (const float*)d_in[2];
  const float* ew2 = (const float*)d_in[3];
  const float* eb2 = (const float*)d_in[4];
  const float* ew3 = (const float*)d_in[5];
  const float* eb3 = (const float*)d_in[6];
  const float* cb  = (const float*)d_in[7];
  const float* dw1 = (const float*)d_in[8];
  const float* db1 = (const float*)d_in[9];
  const float* dw2 = (const float*)d_in[10];
  const float* db2 = (const float*)d_in[11];
  const float* dw3 = (const float*)d_in[12];
  const float* db3 = (const float*)d_in[13];
  float* out = (float*)d_out;
  char*  ws  = (char*)d_ws;

  float*  acc  = (float*)(ws + 0);
  float*  c2   = (float*)(ws + 256);
  float*  wc1p = (float*)(ws + 4096);
  u16*    wc3b = (u16*)  (ws + 8192);        // 16 KB: [hl][ks][nf][lane][8]
  u16*    w3f  = (u16*)  (ws + 24576);
  u16*    w2f  = (u16*)  (ws + 36864);
  u16*    wt1f = (u16*)  (ws + 73728);
  u16*    wt2f = (u16*)  (ws + 147456);
  float*  psum = (float*)(ws + 184320);
  u16*    cbf  = (u16*)  (ws + 262144);
  u16*    z1t  = (u16*)  (ws + 1048576);
  u16*    et   = (u16*)  (ws + 54525952);
  u16*    h1t  = (u16*)  (ws + 1048576);
  u16*    h2t  = (u16*)  (ws + 67108864);
  u16*    z3h  = (u16*)  (ws + 134217728);
  u16*    z3l  = (u16*)  (ws + 142606336);
  float*  xp   = (float*)(ws + 150994944);

  hipMemsetAsync(acc, 0, 64, stream);
  k_prep  <<<3694, 256, 0, stream>>>(ew1, ew2, ew3, dw1, dw2, dw3, cb,
                                     wc1p, wc3b, w3f, c2, w2f, wt1f, wt2f, cbf,
                                     x, xp);
  k_conv1 <<<1024, 256, 0, stream>>>(xp, wc1p, eb1, z1t);
  k_conv23<<<2048, 256, 0, stream>>>(z1t, w2f, eb2, wc3b, eb3, z3h, z3l);
  k_vqpf  <<<1024, 256, 0, stream>>>(z3h, z3l, cbf, c2, cb, et, acc);
  k_convT1<<<1024, 256, 0, stream>>>(et, wt1f, db1, h1t);
  k_convT2<<<1024, 256, 0, stream>>>(h1t, wt2f, db2, h2t);
  k_convT3<<<2048, 256, 0, stream>>>(h2t, w3f, db3, x, out + 3, psum);
  k_fin   <<<1,    256, 0, stream>>>(acc, psum, out);
}

// Round 11
// 253.136 us; speedup vs baseline: 1.0798x; 1.0431x over previous
//
#include <hip/hip_runtime.h>

#define DEV __device__ __forceinline__
typedef unsigned short u16;
typedef __bf16 bf16x8 __attribute__((ext_vector_type(8)));
typedef float f32x4 __attribute__((ext_vector_type(4)));

DEV u16 f2bf(float f) {                      // RNE f32 -> bf16
  unsigned u = __float_as_uint(f);
  u += 0x7FFF + ((u >> 16) & 1);
  return (u16)(u >> 16);
}
DEV float bflo(unsigned u) { return __uint_as_float(u << 16); }          // low u16 -> f32
DEV float bfhi(unsigned u) { return __uint_as_float(u & 0xFFFF0000u); }  // high u16 -> f32

// ---------------- geometry ----------------
// x    [64,3,125,125] fp32
// xp   [64,3,129,128] fp32 zero-padded
// z1t  [64,63,64,32]  bf16
// z3h/z3l [65536][64] bf16 pixel-major hi/lo (conv3 output; z = hi + lo)
// e_t  [64,32,32,64]  bf16  pixel-major
// h1t  [64,64,64,64]  bf16  pixel-major
// h2t  [64,128,128,32] bf16 pixel-major
// xr   [64,3,125,125] fp32
// acc[0] = vq loss sum (atomic from k_vqpf); psum = per-block recon partials

// ---------------- prep + pad fused ----------------
// blocks [0,598): weight/codebook prep. blocks [598,3694): pad x -> xp.
__global__ __launch_bounds__(256) void k_prep(
    const float* __restrict__ ew1, const float* __restrict__ ew2,
    const float* __restrict__ ew3, const float* __restrict__ dw1,
    const float* __restrict__ dw2, const float* __restrict__ dw3,
    const float* __restrict__ cb,
    float* __restrict__ wc1p, u16* __restrict__ wc3b,
    u16* __restrict__ w3f, float* __restrict__ c2,
    u16* __restrict__ w2f, u16* __restrict__ wt1f, u16* __restrict__ wt2f,
    u16* __restrict__ cbf,
    const float* __restrict__ x, float* __restrict__ xp) {
  if (blockIdx.x >= 598) {                 // ---- pad part ----
    int idx = (blockIdx.x - 598) * 256 + threadIdx.x;   // 792576 threads
    int c4 = idx & 31;
    int r  = (idx >> 5) % 129;
    int cbp = (idx >> 5) / 129;
    int ih = r - 1;
    float4 v = make_float4(0.f, 0.f, 0.f, 0.f);
    if ((unsigned)ih < 125u) {
      const float* rp = x + (cbp * 125 + ih) * 125;
      int iw0 = c4 * 4 - 1;
      if (iw0 >= 0)        v.x = rp[iw0];
      if (iw0 + 1 < 125)   v.y = rp[iw0 + 1];
      if (iw0 + 2 < 125)   v.z = rp[iw0 + 2];
      if (iw0 + 3 < 125)   v.w = rp[iw0 + 3];
    }
    *(float4*)(xp + (cbp * 129 + r) * 128 + c4 * 4) = v;
    return;
  }
  int i = blockIdx.x * 256 + threadIdx.x;
  if (i < 864) {
    int cl = i & 7; int t = i >> 3; int tap = t % 9; t /= 9; int ci = t % 3; int cog = t / 3;
    wc1p[i] = ew1[((cog * 8 + cl) * 3 + ci) * 9 + tap];
  } else if (i < 9056) {
    int j = i - 864;                        // wc3b: [hl][ks][nf][lane][8], 8192
    int jj = j & 7; int lane = (j >> 3) & 63; int nf = (j >> 9) & 3; int ks = (j >> 11) & 1; int hl = j >> 12;
    int co = (nf << 4) + (lane & 15);
    int ci = (ks << 5) + ((lane >> 4) << 3) + jj;
    float v = ew3[co * 64 + ci];
    u16 hi = f2bf(v);
    wc3b[j] = hl ? f2bf(v - __uint_as_float((unsigned)hi << 16)) : hi;
  } else if (i < 13152) {
    int j = i - 9056;                       // w3f: [hl][tp][lane][8]
    int jj = j & 7; int lane = (j >> 3) & 63; int tp = (j >> 9) & 3; int hl = j >> 11;
    int kh = tp >> 1, kw = tp & 1;
    int ci = ((lane >> 4) << 3) + jj; int co = lane & 15;
    float wv = (co < 3) ? dw3[((ci * 3 + co) * 2 + kh) * 2 + kw] : 0.f;
    u16 hi = f2bf(wv);
    if (hl == 0) w3f[j] = hi;
    else         w3f[j] = f2bf(wv - __uint_as_float((unsigned)hi << 16));
  } else if (i < 13664) {
    int k = i - 13152;
    const float4* c4 = (const float4*)(cb + (k << 6));
    float s = 0.f;
    #pragma unroll
    for (int q = 0; q < 16; ++q) { float4 v = c4[q]; s += v.x*v.x + v.y*v.y + v.z*v.z + v.w*v.w; }
    c2[k] = s;
  } else if (i < 32096) {
    int j = i - 13664;                      // w2f: [kt][nf][lane][8]
    int jj = j & 7; int lane = (j >> 3) & 63; int nf = (j >> 9) & 3; int kt = j >> 11;
    int kh = kt / 3, kw = kt % 3;
    int ci = ((lane >> 4) << 3) + jj; int co = (nf << 4) + (lane & 15);
    w2f[j] = f2bf(ew2[((co * 32 + ci) * 3 + kh) * 3 + kw]);
  } else if (i < 68960) {
    int j = i - 32096;                      // wt1f: [kt][s][nf][lane][8]
    int jj = j & 7; int lane = (j >> 3) & 63; int nf = (j >> 9) & 3; int s = (j >> 11) & 1; int kt = j >> 12;
    int kh = kt / 3, kw = kt % 3;
    int ci = (s << 5) + ((lane >> 4) << 3) + jj; int co = (nf << 4) + (lane & 15);
    wt1f[j] = f2bf(dw1[((ci * 64 + co) * 3 + kh) * 3 + kw]);
  } else if (i < 87392) {
    int j = i - 68960;                      // wt2f: [kt][s][nf][lane][8]
    int jj = j & 7; int lane = (j >> 3) & 63; int nf = (j >> 9) & 1; int s = (j >> 10) & 1; int kt = j >> 11;
    int kh = kt / 3, kw = kt % 3;
    int ci = (s << 5) + ((lane >> 4) << 3) + jj; int co = (nf << 4) + (lane & 15);
    wt2f[j] = f2bf(dw2[((ci * 32 + co) * 3 + kh) * 3 + kw]);
  } else if (i < 152928) {
    int j = i - 87392;                      // cbf: [hl][ks][nt][lane][8]
    int jj = j & 7; int lane = (j >> 3) & 63; int nt = (j >> 9) & 31; int ks = (j >> 14) & 1; int hl = j >> 15;
    int ci = (ks << 5) + ((lane >> 4) << 3) + jj;
    int code = (nt << 4) + (lane & 15);
    float v = cb[(code << 6) + ci];
    u16 hi = f2bf(v);
    cbf[j] = hl ? f2bf(v - __uint_as_float((unsigned)hi << 16)) : hi;
  }
}

// ---------------- conv1: padded input, all-co blocks, LDS wide stores ----------------
__global__ __launch_bounds__(256) void k_conv1(
    const float* __restrict__ xp, const float* __restrict__ wp,
    const float* __restrict__ bias, u16* __restrict__ z1t) {
  __shared__ u16 st[256 * 34];
  int t = threadIdx.x;
  int slab = blockIdx.x & 15, b = blockIdx.x >> 4;   // grid 1024
  int tx = t & 15, ty = (t >> 4) & 3, cg = t >> 6;
  int oh = slab * 4 + ty;
  int co0 = cg * 8;
  const float* wcg = wp + cg * 216;
  float acc[8][4];
  #pragma unroll
  for (int c = 0; c < 8; ++c) {
    float bv = bias[co0 + c];
    #pragma unroll
    for (int s = 0; s < 4; ++s) acc[c][s] = bv;
  }
  #pragma unroll
  for (int ci = 0; ci < 3; ++ci) {
    #pragma unroll
    for (int kh = 0; kh < 3; ++kh) {
      const float* rp = xp + ((b * 3 + ci) * 129 + (2 * oh + kh)) * 128 + 8 * tx;
      float4 qa = *(const float4*)rp;
      float4 qb = *(const float4*)(rp + 4);
      float v8 = rp[8];
      float v[9] = {qa.x, qa.y, qa.z, qa.w, qb.x, qb.y, qb.z, qb.w, v8};
      #pragma unroll
      for (int kw = 0; kw < 3; ++kw) {
        const float* wq = wcg + (ci * 9 + kh * 3 + kw) * 8;
        float4 wa = *(const float4*)wq;
        float4 wb = *(const float4*)(wq + 4);
        float w8[8] = {wa.x, wa.y, wa.z, wa.w, wb.x, wb.y, wb.z, wb.w};
        #pragma unroll
        for (int s = 0; s < 4; ++s) {
          float in = v[2 * s + kw];
          #pragma unroll
          for (int c = 0; c < 8; ++c) acc[c][s] = fmaf(in, w8[c], acc[c][s]);
        }
      }
    }
  }
  #pragma unroll
  for (int s = 0; s < 4; ++s) {
    bool wok = (tx * 4 + s) < 63;
    unsigned p0 = 0, p1 = 0, p2 = 0, p3 = 0;
    if (wok) {
      p0 = f2bf(fmaxf(acc[0][s], 0.f)) | ((unsigned)f2bf(fmaxf(acc[1][s], 0.f)) << 16);
      p1 = f2bf(fmaxf(acc[2][s], 0.f)) | ((unsigned)f2bf(fmaxf(acc[3][s], 0.f)) << 16);
      p2 = f2bf(fmaxf(acc[4][s], 0.f)) | ((unsigned)f2bf(fmaxf(acc[5][s], 0.f)) << 16);
      p3 = f2bf(fmaxf(acc[6][s], 0.f)) | ((unsigned)f2bf(fmaxf(acc[7][s], 0.f)) << 16);
    }
    int lpix = tx * 16 + ty * 4 + s;
    *(uint4*)&st[lpix * 34 + co0] = make_uint4(p0, p1, p2, p3);
  }
  __syncthreads();
  {
    int p = t;
    int ow = (p >> 4) * 4 + (p & 3);
    int ohl = (p >> 2) & 3;
    int oho = slab * 4 + ohl;
    if (oho < 63) {
      const u16* lp = &st[p * 34];
      uint4 a0 = *(const uint4*)(lp);
      uint4 a1 = *(const uint4*)(lp + 8);
      uint4 a2 = *(const uint4*)(lp + 16);
      uint4 a3 = *(const uint4*)(lp + 24);
      uint4* gp = (uint4*)(z1t + ((b * 63 + oho) * 64 + ow) * 32);
      gp[0] = a0; gp[1] = a1; gp[2] = a2; gp[3] = a3;
    }
  }
}

// ---------------- conv2+conv3 fused: stencil MFMA -> LDS hi/lo -> 1x1 MFMA -> z3h/z3l ----------------
__global__ __launch_bounds__(256) void k_conv23(
    const u16* __restrict__ z1t, const u16* __restrict__ wf,
    const float* __restrict__ b2, const u16* __restrict__ wcb,
    const float* __restrict__ b3,
    u16* __restrict__ z3h, u16* __restrict__ z3l) {
  __shared__ u16 sh[32 * 72];
  __shared__ u16 sl[32 * 72];
  __shared__ u16 lh[32 * 72];
  __shared__ u16 ll[32 * 72];
  int t = threadIdx.x;
  int lane = t & 63, wv = t >> 6;
  int n = lane & 15, q = lane >> 4;
  int raw = blockIdx.x;                           // grid 2048 = 8*256
  int wg = ((raw & 7) << 8) + (raw >> 3);         // bijective XCD swizzle
  int oh = wg & 31, b = wg >> 5;
  int xt = wv & 1, ch = wv >> 1;
  int xA = xt * 16 + n;
  f32x4 acc[2] = {{0,0,0,0},{0,0,0,0}};
  #pragma unroll
  for (int kh = 0; kh < 3; ++kh) {
    int ih = 2 * oh - 1 + kh;
    bool yok = (unsigned)ih < 63u;
    #pragma unroll
    for (int kw = 0; kw < 3; ++kw) {
      int iw = 2 * xA - 1 + kw;
      bool ok = yok && (iw >= 0);
      bf16x8 a = {};
      if (ok) a = *(const bf16x8*)(z1t + ((b * 63 + ih) * 64 + iw) * 32 + q * 8);
      int kt = kh * 3 + kw;
      const u16* wb = wf + ((kt << 2) + (ch << 1)) * 512 + lane * 8;
      bf16x8 b0 = *(const bf16x8*)wb;
      bf16x8 b1 = *(const bf16x8*)(wb + 512);
      acc[0] = __builtin_amdgcn_mfma_f32_16x16x32_bf16(a, b0, acc[0], 0, 0, 0);
      acc[1] = __builtin_amdgcn_mfma_f32_16x16x32_bf16(a, b1, acc[1], 0, 0, 0);
    }
  }
  #pragma unroll
  for (int j = 0; j < 2; ++j) {
    int co = ((ch << 1) + j) * 16 + n;
    float bv = b2[co];
    #pragma unroll
    for (int r = 0; r < 4; ++r) {
      int ow = xt * 16 + q * 4 + r;
      float v = fmaxf(acc[j][r] + bv, 0.f);
      u16 h = f2bf(v);
      u16 l = f2bf(v - __uint_as_float((unsigned)h << 16));
      sh[ow * 72 + co] = h;
      sl[ow * 72 + co] = l;
    }
  }
  __syncthreads();
  // ---- conv3 (1x1) from LDS: wave wv = nf (16 co), 2 mt of 16 px ----
  {
    const u16* wb = wcb + (wv << 9) + lane * 8;
    bf16x8 Bh0 = *(const bf16x8*)wb;
    bf16x8 Bh1 = *(const bf16x8*)(wb + 2048);
    bf16x8 Bl0 = *(const bf16x8*)(wb + 4096);
    bf16x8 Bl1 = *(const bf16x8*)(wb + 6144);
    int co = (wv << 4) + n;
    float bv = b3[co];
    #pragma unroll
    for (int mti = 0; mti < 2; ++mti) {
      int base = (mti * 16 + n) * 72 + q * 8;
      bf16x8 Ah0 = *(const bf16x8*)&sh[base];
      bf16x8 Ah1 = *(const bf16x8*)&sh[base + 32];
      bf16x8 Al0 = *(const bf16x8*)&sl[base];
      bf16x8 Al1 = *(const bf16x8*)&sl[base + 32];
      f32x4 a = {0.f, 0.f, 0.f, 0.f};
      a = __builtin_amdgcn_mfma_f32_16x16x32_bf16(Ah0, Bh0, a, 0, 0, 0);
      a = __builtin_amdgcn_mfma_f32_16x16x32_bf16(Ah1, Bh1, a, 0, 0, 0);
      a = __builtin_amdgcn_mfma_f32_16x16x32_bf16(Al0, Bh0, a, 0, 0, 0);
      a = __builtin_amdgcn_mfma_f32_16x16x32_bf16(Al1, Bh1, a, 0, 0, 0);
      a = __builtin_amdgcn_mfma_f32_16x16x32_bf16(Ah0, Bl0, a, 0, 0, 0);
      a = __builtin_amdgcn_mfma_f32_16x16x32_bf16(Ah1, Bl1, a, 0, 0, 0);
      int pxl0 = mti * 16 + q * 4;
      #pragma unroll
      for (int r = 0; r < 4; ++r) {
        float v = a[r] + bv;
        u16 h = f2bf(v);
        u16 l = f2bf(v - __uint_as_float((unsigned)h << 16));
        lh[(pxl0 + r) * 72 + co] = h;
        ll[(pxl0 + r) * 72 + co] = l;
      }
    }
  }
  __syncthreads();
  {
    int px = t >> 3, sg = t & 7;
    uint4 hv = *(const uint4*)&lh[px * 72 + sg * 8];
    uint4 lv = *(const uint4*)&ll[px * 72 + sg * 8];
    long gp = ((long)(b * 1024 + oh * 32 + px) << 6) + sg * 8;
    *(uint4*)(z3h + gp) = hv;
    *(uint4*)(z3l + gp) = lv;
  }
}

// ---------------- VQ fused: argmin 8 mt (128 px/block, grid 512) + gather/loss/et ----------------
// 2x px per block halves codebook L2 traffic and doubles MFMA work per B-load
// cluster (48 MFMA/nt) to bury L2 latency. Tie-break identical to reference.
__global__ __launch_bounds__(256) void k_vqpf(
    const u16* __restrict__ z3h, const u16* __restrict__ z3l,
    const u16* __restrict__ cbf, const float* __restrict__ c2v,
    const float* __restrict__ cb,
    u16* __restrict__ et, float* __restrict__ acc) {
  int t = threadIdx.x;
  int lane = t & 63, wv = t >> 6;
  int n = lane & 15, q = lane >> 4;
  int p0 = blockIdx.x * 128;                        // grid 512
  bf16x8 Ah[8][2], Al[8][2];
  #pragma unroll
  for (int mt = 0; mt < 8; ++mt) {
    const u16* ap = z3h + (p0 + mt * 16 + n) * 64 + q * 8;
    const u16* al = z3l + (p0 + mt * 16 + n) * 64 + q * 8;
    Ah[mt][0] = *(const bf16x8*)ap;  Ah[mt][1] = *(const bf16x8*)(ap + 32);
    Al[mt][0] = *(const bf16x8*)al;  Al[mt][1] = *(const bf16x8*)(al + 32);
  }
  float bs[8][4]; int bix[8][4];
  #pragma unroll
  for (int mt = 0; mt < 8; ++mt)
    #pragma unroll
    for (int r = 0; r < 4; ++r) { bs[mt][r] = 3.4e38f; bix[mt][r] = 0; }
  const u16* bp = cbf + lane * 8;
  int ntb = wv * 8;
  for (int nt0 = 0; nt0 < 8; ++nt0) {               // rolled
    int nt = ntb + nt0;
    bf16x8 Bh0 = *(const bf16x8*)(bp + (nt << 9));
    bf16x8 Bh1 = *(const bf16x8*)(bp + ((32 + nt) << 9));
    bf16x8 Bl0 = *(const bf16x8*)(bp + ((64 + nt) << 9));
    bf16x8 Bl1 = *(const bf16x8*)(bp + ((96 + nt) << 9));
    float c2 = c2v[(nt << 4) + n];
    #pragma unroll
    for (int mt = 0; mt < 8; ++mt) {
      f32x4 a = {0.f, 0.f, 0.f, 0.f};
      a = __builtin_amdgcn_mfma_f32_16x16x32_bf16(Ah[mt][0], Bh0, a, 0, 0, 0);
      a = __builtin_amdgcn_mfma_f32_16x16x32_bf16(Ah[mt][1], Bh1, a, 0, 0, 0);
      a = __builtin_amdgcn_mfma_f32_16x16x32_bf16(Al[mt][0], Bh0, a, 0, 0, 0);
      a = __builtin_amdgcn_mfma_f32_16x16x32_bf16(Al[mt][1], Bh1, a, 0, 0, 0);
      a = __builtin_amdgcn_mfma_f32_16x16x32_bf16(Ah[mt][0], Bl0, a, 0, 0, 0);
      a = __builtin_amdgcn_mfma_f32_16x16x32_bf16(Ah[mt][1], Bl1, a, 0, 0, 0);
      int idx = (nt << 4) + n;
      #pragma unroll
      for (int r = 0; r < 4; ++r) {
        float sc = fmaf(-2.f, a[r], c2);
        if (sc < bs[mt][r]) { bs[mt][r] = sc; bix[mt][r] = idx; }
      }
    }
  }
  #pragma unroll
  for (int off = 8; off > 0; off >>= 1) {
    #pragma unroll
    for (int mt = 0; mt < 8; ++mt)
      #pragma unroll
      for (int r = 0; r < 4; ++r) {
        float os = __shfl_xor(bs[mt][r], off, 16);
        int oi = __shfl_xor(bix[mt][r], off, 16);
        if (os < bs[mt][r] || (os == bs[mt][r] && oi < bix[mt][r])) {
          bs[mt][r] = os; bix[mt][r] = oi;
        }
      }
  }
  __shared__ float ls[4][128];
  __shared__ int   li[4][128];
  __shared__ int   lfin[128];
  if (n == 0) {
    #pragma unroll
    for (int mt = 0; mt < 8; ++mt)
      #pragma unroll
      for (int r = 0; r < 4; ++r) {
        int px = mt * 16 + q * 4 + r;
        ls[wv][px] = bs[mt][r];
        li[wv][px] = bix[mt][r];
      }
  }
  __syncthreads();
  if (t < 128) {
    float best = ls[0][t]; int bi = li[0][t];
    #pragma unroll
    for (int w = 1; w < 4; ++w) {
      float s = ls[w][t]; int ii = li[w][t];
      if (s < best || (s == best && ii < bi)) { best = s; bi = ii; }
    }
    lfin[t] = bi;
  }
  __syncthreads();
  // ---- phase 2: gather codebook, write et, e-q loss (2 halves of 64 px) ----
  float lsum = 0.f;
  #pragma unroll
  for (int half = 0; half < 2; ++half) {
    int pxl = (half << 6) + (t >> 2);
    int ciq = t & 3;                        // 4 channel-quads (16 ch each)
    int ng = p0 + pxl;
    int bi = lfin[pxl];
    const u16* zh = z3h + ((long)ng << 6) + (ciq << 4);
    const u16* zl = z3l + ((long)ng << 6) + (ciq << 4);
    uint4 h0v = *(const uint4*)zh, h1v = *(const uint4*)(zh + 8);
    uint4 l0v = *(const uint4*)zl, l1v = *(const uint4*)(zl + 8);
    unsigned hw_[8] = {h0v.x, h0v.y, h0v.z, h0v.w, h1v.x, h1v.y, h1v.z, h1v.w};
    unsigned lw_[8] = {l0v.x, l0v.y, l0v.z, l0v.w, l1v.x, l1v.y, l1v.z, l1v.w};
    const float4* cq = (const float4*)(cb + (bi << 6) + (ciq << 4));
    unsigned pk[8];
    #pragma unroll
    for (int i = 0; i < 4; ++i) {
      float4 c = cq[i];
      float z0 = bflo(hw_[2 * i])     + bflo(lw_[2 * i]);
      float z1 = bfhi(hw_[2 * i])     + bfhi(lw_[2 * i]);
      float z2 = bflo(hw_[2 * i + 1]) + bflo(lw_[2 * i + 1]);
      float z3 = bfhi(hw_[2 * i + 1]) + bfhi(lw_[2 * i + 1]);
      float df;
      df = c.x - z0; lsum = fmaf(df, df, lsum);
      df = c.y - z1; lsum = fmaf(df, df, lsum);
      df = c.z - z2; lsum = fmaf(df, df, lsum);
      df = c.w - z3; lsum = fmaf(df, df, lsum);
      pk[2 * i]     = f2bf(c.x) | ((unsigned)f2bf(c.y) << 16);
      pk[2 * i + 1] = f2bf(c.z) | ((unsigned)f2bf(c.w) << 16);
    }
    uint4* ep = (uint4*)(et + ((long)ng << 6) + (ciq << 4));
    ep[0] = make_uint4(pk[0], pk[1], pk[2], pk[3]);
    ep[1] = make_uint4(pk[4], pk[5], pk[6], pk[7]);
  }
  __shared__ float red[256];
  red[t] = lsum; __syncthreads();
  #pragma unroll
  for (int s = 128; s > 0; s >>= 1) {
    if (t < s) red[t] += red[t + s];
    __syncthreads();
  }
  if (t == 0) atomicAdd(acc + 0, red[0]);
}

// ---------------- convT1: cog-split, LDS weights, XCD-swizzled ----------------
__global__ __launch_bounds__(256) void k_convT1(
    const u16* __restrict__ et, const u16* __restrict__ wf,
    const float* __restrict__ bias, u16* __restrict__ h1t) {
  __shared__ u16 wl[36 * 512];      // 36864 B
  __shared__ u16 st[4][64 * 34];    // 17408 B
  int t = threadIdx.x;
  int lane = t & 63, wv = t >> 6;
  int yw = wv & 1, xt = wv >> 1;
  int raw = blockIdx.x;                          // grid 1024 = 8*128
  int wg = ((raw & 7) << 7) + (raw >> 3);        // bijective XCD swizzle
  int cog = wg & 1;
  int yg = (wg >> 1) & 7;
  int b = wg >> 4;
  {
    const uint4* gw = (const uint4*)wf;
    uint4* lw = (uint4*)wl;
    #pragma unroll
    for (int k = 0; k < 9; ++k) {
      int i = t + 256 * k;
      int slot = i >> 6, within = i & 63;
      int kt = slot >> 2, j = (slot >> 1) & 1, ks = slot & 1;
      int goff = (kt << 12) + (((ks << 2) + (cog << 1) + j) << 9);
      lw[i] = gw[(goff >> 3) + within];
    }
  }
  int n = lane & 15, q = lane >> 4;
  int m = xt * 16 + n;
  __syncthreads();
  for (int iter = 0; iter < 2; ++iter) {
    int y = yg * 4 + iter * 2 + yw;
    const u16* base0 = et + (((b * 32 + y) * 32) << 6) + q * 8;
    bf16x8 P00a, P00b, P01a = {}, P01b = {}, P10a = {}, P10b = {}, P11a = {}, P11b = {};
    { const u16* p = base0 + (m << 6); P00a = *(const bf16x8*)p; P00b = *(const bf16x8*)(p + 32); }
    if (m + 1 < 32) { const u16* p = base0 + ((m + 1) << 6); P01a = *(const bf16x8*)p; P01b = *(const bf16x8*)(p + 32); }
    if (y + 1 < 32) {
      const u16* base1 = base0 + (32 << 6);
      { const u16* p = base1 + (m << 6); P10a = *(const bf16x8*)p; P10b = *(const bf16x8*)(p + 32); }
      if (m + 1 < 32) { const u16* p = base1 + ((m + 1) << 6); P11a = *(const bf16x8*)p; P11b = *(const bf16x8*)(p + 32); }
    }
    f32x4 accE[2][2] = {};  // [j][pwi]
    f32x4 accO[2][2] = {};
    #pragma unroll
    for (int kw = 0; kw < 3; ++kw) {
      int pwi = (kw == 1) ? 0 : 1;
      bf16x8 A0a = (kw == 0) ? P01a : P00a;
      bf16x8 A0b = (kw == 0) ? P01b : P00b;
      bf16x8 A1a = (kw == 0) ? P11a : P10a;
      bf16x8 A1b = (kw == 0) ? P11b : P10b;
      #pragma unroll
      for (int j = 0; j < 2; ++j) {
        const u16* wE  = wl + ((((3 + kw) << 2) + (j << 1)) << 9) + lane * 8;
        const u16* wO0 = wl + (((kw << 2) + (j << 1)) << 9) + lane * 8;
        const u16* wO2 = wl + ((((6 + kw) << 2) + (j << 1)) << 9) + lane * 8;
        bf16x8 bE0 = *(const bf16x8*)wE;
        bf16x8 bE1 = *(const bf16x8*)(wE + 512);
        accE[j][pwi] = __builtin_amdgcn_mfma_f32_16x16x32_bf16(A0a, bE0, accE[j][pwi], 0, 0, 0);
        accE[j][pwi] = __builtin_amdgcn_mfma_f32_16x16x32_bf16(A0b, bE1, accE[j][pwi], 0, 0, 0);
        bf16x8 bO00 = *(const bf16x8*)wO0;
        bf16x8 bO01 = *(const bf16x8*)(wO0 + 512);
        accO[j][pwi] = __builtin_amdgcn_mfma_f32_16x16x32_bf16(A1a, bO00, accO[j][pwi], 0, 0, 0);
        accO[j][pwi] = __builtin_amdgcn_mfma_f32_16x16x32_bf16(A1b, bO01, accO[j][pwi], 0, 0, 0);
        bf16x8 bO20 = *(const bf16x8*)wO2;
        bf16x8 bO21 = *(const bf16x8*)(wO2 + 512);
        accO[j][pwi] = __builtin_amdgcn_mfma_f32_16x16x32_bf16(A0a, bO20, accO[j][pwi], 0, 0, 0);
        accO[j][pwi] = __builtin_amdgcn_mfma_f32_16x16x32_bf16(A0b, bO21, accO[j][pwi], 0, 0, 0);
      }
    }
    #pragma unroll
    for (int j = 0; j < 2; ++j) {
      int col = j * 16 + n;
      float bv = bias[cog * 32 + col];
      #pragma unroll
      for (int pw = 0; pw < 2; ++pw)
        #pragma unroll
        for (int r = 0; r < 4; ++r) {
          int ow = 2 * (xt * 16 + q * 4 + r) + pw;
          st[yw * 2 + 0][ow * 34 + col] = f2bf(fmaxf(accE[j][pw][r] + bv, 0.f));
          st[yw * 2 + 1][ow * 34 + col] = f2bf(fmaxf(accO[j][pw][r] + bv, 0.f));
        }
    }
    __syncthreads();
    {
      int row = t >> 6, ow = t & 63;   // 4 rows x 64 ow
      const u16* lp = &st[row][ow * 34];
      uint4* gp = (uint4*)(h1t + (((b * 64 + yg * 8 + iter * 4 + row) * 64 + ow) << 6) + cog * 32);
      gp[0] = *(const uint4*)(lp);
      gp[1] = *(const uint4*)(lp + 8);
      gp[2] = *(const uint4*)(lp + 16);
      gp[3] = *(const uint4*)(lp + 24);
    }
    __syncthreads();
  }
}

// ---------------- convT2: LDS weights, 4 y-pairs/block loop, XCD-swizzled ----------------
__global__ __launch_bounds__(256) void k_convT2(
    const u16* __restrict__ h1t, const u16* __restrict__ wf,
    const float* __restrict__ bias, u16* __restrict__ h2t) {
  __shared__ u16 wl[18432];         // 36864 B
  __shared__ u16 st[2][128 * 34];   // 17408 B
  int t = threadIdx.x;
  int lane = t & 63, xt = t >> 6;
  int n = lane & 15, q = lane >> 4;
  int raw = blockIdx.x;                          // grid 1024 = 8*128
  int wg = ((raw & 7) << 7) + (raw >> 3);        // bijective XCD swizzle
  int yg = wg & 15, b = wg >> 4;
  {
    const uint4* gw = (const uint4*)wf;
    uint4* lw = (uint4*)wl;
    #pragma unroll
    for (int k = 0; k < 9; ++k) lw[t + 256 * k] = gw[t + 256 * k];
  }
  int m = xt * 16 + n;
  __syncthreads();
  for (int yp = 0; yp < 4; ++yp) {
    int y = yg * 4 + yp;
    const u16* base0 = h1t + (((b * 64 + y) * 64) << 6) + q * 8;
    bf16x8 P00a, P00b, P01a = {}, P01b = {}, P10a = {}, P10b = {}, P11a = {}, P11b = {};
    { const u16* p = base0 + (m << 6); P00a = *(const bf16x8*)p; P00b = *(const bf16x8*)(p + 32); }
    if (m + 1 < 64) { const u16* p = base0 + ((m + 1) << 6); P01a = *(const bf16x8*)p; P01b = *(const bf16x8*)(p + 32); }
    if (y + 1 < 64) {
      const u16* base1 = base0 + (64 << 6);
      { const u16* p = base1 + (m << 6); P10a = *(const bf16x8*)p; P10b = *(const bf16x8*)(p + 32); }
      if (m + 1 < 64) { const u16* p = base1 + ((m + 1) << 6); P11a = *(const bf16x8*)p; P11b = *(const bf16x8*)(p + 32); }
    }
    f32x4 accE[2][2] = {};  // [nf][pwi]
    f32x4 accO[2][2] = {};
    #pragma unroll
    for (int kw = 0; kw < 3; ++kw) {
      int pwi = (kw == 1) ? 0 : 1;
      bf16x8 A0a = (kw == 0) ? P01a : P00a;
      bf16x8 A0b = (kw == 0) ? P01b : P00b;
      bf16x8 A1a = (kw == 0) ? P11a : P10a;
      bf16x8 A1b = (kw == 0) ? P11b : P10b;
      const u16* wbE = wl + ((3 + kw) << 11) + lane * 8;
      const u16* wbO0 = wl + (kw << 11) + lane * 8;
      const u16* wbO2 = wl + ((6 + kw) << 11) + lane * 8;
      #pragma unroll
      for (int nf = 0; nf < 2; ++nf) {
        bf16x8 bE0 = *(const bf16x8*)(wbE + nf * 512);
        bf16x8 bE1 = *(const bf16x8*)(wbE + (2 + nf) * 512);
        accE[nf][pwi] = __builtin_amdgcn_mfma_f32_16x16x32_bf16(A0a, bE0, accE[nf][pwi], 0, 0, 0);
        accE[nf][pwi] = __builtin_amdgcn_mfma_f32_16x16x32_bf16(A0b, bE1, accE[nf][pwi], 0, 0, 0);
        bf16x8 bO00 = *(const bf16x8*)(wbO0 + nf * 512);
        bf16x8 bO01 = *(const bf16x8*)(wbO0 + (2 + nf) * 512);
        accO[nf][pwi] = __builtin_amdgcn_mfma_f32_16x16x32_bf16(A1a, bO00, accO[nf][pwi], 0, 0, 0);
        accO[nf][pwi] = __builtin_amdgcn_mfma_f32_16x16x32_bf16(A1b, bO01, accO[nf][pwi], 0, 0, 0);
        bf16x8 bO20 = *(const bf16x8*)(wbO2 + nf * 512);
        bf16x8 bO21 = *(const bf16x8*)(wbO2 + (2 + nf) * 512);
        accO[nf][pwi] = __builtin_amdgcn_mfma_f32_16x16x32_bf16(A0a, bO20, accO[nf][pwi], 0, 0, 0);
        accO[nf][pwi] = __builtin_amdgcn_mfma_f32_16x16x32_bf16(A0b, bO21, accO[nf][pwi], 0, 0, 0);
      }
    }
    #pragma unroll
    for (int nf = 0; nf < 2; ++nf) {
      int co = nf * 16 + n;
      float bv = bias[co];
      #pragma unroll
      for (int pw = 0; pw < 2; ++pw)
        #pragma unroll
        for (int r = 0; r < 4; ++r) {
          int ow = 2 * (xt * 16 + q * 4 + r) + pw;
          st[0][ow * 34 + co] = f2bf(fmaxf(accE[nf][pw][r] + bv, 0.f));
          st[1][ow * 34 + co] = f2bf(fmaxf(accO[nf][pw][r] + bv, 0.f));
        }
    }
    __syncthreads();
    {
      int ow = t >> 1, sg = t & 1;
      #pragma unroll
      for (int l = 0; l < 2; ++l) {
        const u16* lp = &st[l][ow * 34 + sg * 16];
        unsigned w0 = *(const unsigned*)(lp + 0), w1 = *(const unsigned*)(lp + 2);
        unsigned w2 = *(const unsigned*)(lp + 4), w3 = *(const unsigned*)(lp + 6);
        unsigned w4 = *(const unsigned*)(lp + 8), w5 = *(const unsigned*)(lp + 10);
        unsigned w6 = *(const unsigned*)(lp + 12), w7 = *(const unsigned*)(lp + 14);
        uint4* gp = (uint4*)(h2t + ((((b * 128 + yg * 8 + yp * 2 + l) * 128) + ow) << 5) + sg * 16);
        gp[0] = make_uint4(w0, w1, w2, w3);
        gp[1] = make_uint4(w4, w5, w6, w7);
      }
    }
    __syncthreads();
  }
}

// ---------------- convT3 + recon loss: 5-rows-once, 4 indep MFMA chains ----------------
__global__ __launch_bounds__(256) void k_convT3(
    const u16* __restrict__ h2t, const u16* __restrict__ w3f,
    const float* __restrict__ bias, const float* __restrict__ x,
    float* __restrict__ xr, float* __restrict__ psum) {
  int t = threadIdx.x;
  int lane = t & 63, wv = t >> 6;
  int n = lane & 15, q = lane >> 4;
  int raw = blockIdx.x;                          // grid 2048 = 8*256
  int wg = ((raw & 7) << 8) + (raw >> 3);        // bijective XCD swizzle
  int rg = wg & 31, b = wg >> 5;
  int oh0 = rg * 4;
  const u16* wbp = w3f + lane * 8;
  bf16x8 Bh0 = *(const bf16x8*)(wbp);
  bf16x8 Bh1 = *(const bf16x8*)(wbp + 512);
  bf16x8 Bh2 = *(const bf16x8*)(wbp + 1024);
  bf16x8 Bh3 = *(const bf16x8*)(wbp + 1536);
  bf16x8 Bl0 = *(const bf16x8*)(wbp + 2048);
  bf16x8 Bl1 = *(const bf16x8*)(wbp + 2560);
  bf16x8 Bl2 = *(const bf16x8*)(wbp + 3072);
  bf16x8 Bl3 = *(const bf16x8*)(wbp + 3584);
  float bv = (n < 3) ? bias[n] : 0.f;
  float lsum = 0.f;
  if (oh0 <= 121) {
    const u16* rbase = h2t + (((long)b * 128 + (oh0 + 1)) << 12) + q * 8;
    #pragma unroll
    for (int ti = 0; ti < 2; ++ti) {
      int tt = wv + ti * 4;
      int c1 = tt * 16 + n + 1;
      int c2 = c1 + 1;
      bf16x8 A[5][2];
      #pragma unroll
      for (int j = 0; j < 5; ++j) {
        A[j][0] = (bf16x8){}; A[j][1] = (bf16x8){};
        const u16* rp = rbase + ((long)j << 12);
        if (c1 < 128) A[j][0] = *(const bf16x8*)(rp + (c1 << 5));
        if (c2 < 128) A[j][1] = *(const bf16x8*)(rp + (c2 << 5));
      }
      f32x4 ac[4] = {};
      #pragma unroll
      for (int k = 0; k < 4; ++k) {
        ac[k] = __builtin_amdgcn_mfma_f32_16x16x32_bf16(A[k][0],     Bh3, ac[k], 0, 0, 0);
        ac[k] = __builtin_amdgcn_mfma_f32_16x16x32_bf16(A[k][1],     Bh2, ac[k], 0, 0, 0);
        ac[k] = __builtin_amdgcn_mfma_f32_16x16x32_bf16(A[k + 1][0], Bh1, ac[k], 0, 0, 0);
        ac[k] = __builtin_amdgcn_mfma_f32_16x16x32_bf16(A[k + 1][1], Bh0, ac[k], 0, 0, 0);
        ac[k] = __builtin_amdgcn_mfma_f32_16x16x32_bf16(A[k][0],     Bl3, ac[k], 0, 0, 0);
        ac[k] = __builtin_amdgcn_mfma_f32_16x16x32_bf16(A[k][1],     Bl2, ac[k], 0, 0, 0);
        ac[k] = __builtin_amdgcn_mfma_f32_16x16x32_bf16(A[k + 1][0], Bl1, ac[k], 0, 0, 0);
        ac[k] = __builtin_amdgcn_mfma_f32_16x16x32_bf16(A[k + 1][1], Bl0, ac[k], 0, 0, 0);
      }
      if (n < 3) {
        int ow0 = tt * 16 + q * 4;
        #pragma unroll
        for (int k = 0; k < 4; ++k) {
          int oh = oh0 + k;
          int o = b * 46875 + n * 15625 + oh * 125 + ow0;
          if (ow0 + 3 < 125) {
            float4 v = make_float4(ac[k][0] + bv, ac[k][1] + bv, ac[k][2] + bv, ac[k][3] + bv);
            float4 xv = *(const float4*)(x + o);
            *(float4*)(xr + o) = v;
            float d0 = v.x - xv.x, d1 = v.y - xv.y, d2 = v.z - xv.z, d3 = v.w - xv.w;
            lsum += d0 * d0 + d1 * d1 + d2 * d2 + d3 * d3;
          } else {
            #pragma unroll
            for (int r = 0; r < 4; ++r) {
              if (ow0 + r < 125) {
                float v = ac[k][r] + bv;
                xr[o + r] = v;
                float d = v - x[o + r];
                lsum = fmaf(d, d, lsum);
              }
            }
          }
        }
      }
    }
  } else {
    int oh = 124;
    const u16* row1 = h2t + (((long)b * 128 + (oh + 1)) << 12) + q * 8;
    const u16* row2 = row1 + 4096;
    #pragma unroll
    for (int ti = 0; ti < 2; ++ti) {
      int tt = wv + ti * 4;
      int c1 = tt * 16 + n + 1;
      int c2 = c1 + 1;
      bf16x8 a11 = {}, a12 = {}, a21 = {}, a22 = {};
      if (c1 < 128) { a11 = *(const bf16x8*)(row1 + (c1 << 5));
                      a21 = *(const bf16x8*)(row2 + (c1 << 5)); }
      if (c2 < 128) { a12 = *(const bf16x8*)(row1 + (c2 << 5));
                      a22 = *(const bf16x8*)(row2 + (c2 << 5)); }
      f32x4 a = {0.f, 0.f, 0.f, 0.f};
      a = __builtin_amdgcn_mfma_f32_16x16x32_bf16(a11, Bh3, a, 0, 0, 0);
      a = __builtin_amdgcn_mfma_f32_16x16x32_bf16(a12, Bh2, a, 0, 0, 0);
      a = __builtin_amdgcn_mfma_f32_16x16x32_bf16(a21, Bh1, a, 0, 0, 0);
      a = __builtin_amdgcn_mfma_f32_16x16x32_bf16(a22, Bh0, a, 0, 0, 0);
      a = __builtin_amdgcn_mfma_f32_16x16x32_bf16(a11, Bl3, a, 0, 0, 0);
      a = __builtin_amdgcn_mfma_f32_16x16x32_bf16(a12, Bl2, a, 0, 0, 0);
      a = __builtin_amdgcn_mfma_f32_16x16x32_bf16(a21, Bl1, a, 0, 0, 0);
      a = __builtin_amdgcn_mfma_f32_16x16x32_bf16(a22, Bl0, a, 0, 0, 0);
      if (n < 3) {
        int ow0 = tt * 16 + q * 4;
        int o = b * 46875 + n * 15625 + oh * 125 + ow0;
        if (ow0 + 3 < 125) {
          float4 v = make_float4(a[0] + bv, a[1] + bv, a[2] + bv, a[3] + bv);
          float4 xv = *(const float4*)(x + o);
          *(float4*)(xr + o) = v;
          float d0 = v.x - xv.x, d1 = v.y - xv.y, d2 = v.z - xv.z, d3 = v.w - xv.w;
          lsum += d0 * d0 + d1 * d1 + d2 * d2 + d3 * d3;
        } else {
          #pragma unroll
          for (int r = 0; r < 4; ++r) {
            if (ow0 + r < 125) {
              float v = a[r] + bv;
              xr[o + r] = v;
              float d = v - x[o + r];
              lsum = fmaf(d, d, lsum);
            }
          }
        }
      }
    }
  }
  __shared__ float red[256];
  red[t] = lsum; __syncthreads();
  #pragma unroll
  for (int s = 128; s > 0; s >>= 1) {
    if (t < s) red[t] += red[t + s];
    __syncthreads();
  }
  if (t == 0) psum[raw] = red[0];
}

// ---------------- finalize: reduce 2048 partials + vq loss ----------------
__global__ __launch_bounds__(256) void k_fin(
    const float* __restrict__ acc, const float* __restrict__ psum,
    float* __restrict__ out) {
  int t = threadIdx.x;
  float s = 0.f;
  for (int i = t; i < 2048; i += 256) s += psum[i];
  __shared__ float red[256];
  red[t] = s; __syncthreads();
  #pragma unroll
  for (int k = 128; k > 0; k >>= 1) {
    if (t < k) red[t] += red[t + k];
    __syncthreads();
  }
  if (t == 0) {
    float eq  = 1.25f * acc[0] / 4194304.0f;
    float rec = red[0];
    out[0] = eq + rec;
    out[1] = eq;
    out[2] = rec;
  }
}

extern "C" void kernel_launch(void* const* d_in, const int* in_sizes, int n_in,
                              void* d_out, int out_size, void* d_ws, size_t ws_size,
                              hipStream_t stream) {
  (void)in_sizes; (void)n_in; (void)out_size; (void)ws_size;
  const float* x   = (const float*)d_in[0];
  const float* ew1 = (const float*)d_in[1];
  const float* eb1 = (const float*)d_in[2];
  const float* ew2 = (const float*)d_in[3];
  const float* eb2 = (const float*)d_in[4];
  const float* ew3 = (const float*)d_in[5];
  const float* eb3 = (const float*)d_in[6];
  const float* cb  = (const float*)d_in[7];
  const float* dw1 = (const float*)d_in[8];
  const float* db1 = (const float*)d_in[9];
  const float* dw2 = (const float*)d_in[10];
  const float* db2 = (const float*)d_in[11];
  const float* dw3 = (const float*)d_in[12];
  const float* db3 = (const float*)d_in[13];
  float* out = (float*)d_out;
  char*  ws  = (char*)d_ws;

  float*  acc  = (float*)(ws + 0);
  float*  c2   = (float*)(ws + 256);
  float*  wc1p = (float*)(ws + 4096);
  u16*    wc3b = (u16*)  (ws + 8192);        // 16 KB: [hl][ks][nf][lane][8]
  u16*    w3f  = (u16*)  (ws + 24576);
  u16*    w2f  = (u16*)  (ws + 36864);
  u16*    wt1f = (u16*)  (ws + 73728);
  u16*    wt2f = (u16*)  (ws + 147456);
  float*  psum = (float*)(ws + 184320);
  u16*    cbf  = (u16*)  (ws + 262144);
  u16*    z1t  = (u16*)  (ws + 1048576);
  u16*    et   = (u16*)  (ws + 54525952);
  u16*    h1t  = (u16*)  (ws + 1048576);
  u16*    h2t  = (u16*)  (ws + 67108864);
  u16*    z3h  = (u16*)  (ws + 134217728);
  u16*    z3l  = (u16*)  (ws + 142606336);
  float*  xp   = (float*)(ws + 150994944);

  hipMemsetAsync(acc, 0, 64, stream);
  k_prep  <<<3694, 256, 0, stream>>>(ew1, ew2, ew3, dw1, dw2, dw3, cb,
                                     wc1p, wc3b, w3f, c2, w2f, wt1f, wt2f, cbf,
                                     x, xp);
  k_conv1 <<<1024, 256, 0, stream>>>(xp, wc1p, eb1, z1t);
  k_conv23<<<2048, 256, 0, stream>>>(z1t, w2f, eb2, wc3b, eb3, z3h, z3l);
  k_vqpf  <<<512,  256, 0, stream>>>(z3h, z3l, cbf, c2, cb, et, acc);
  k_convT1<<<1024, 256, 0, stream>>>(et, wt1f, db1, h1t);
  k_convT2<<<1024, 256, 0, stream>>>(h1t, wt2f, db2, h2t);
  k_convT3<<<2048, 256, 0, stream>>>(h2t, w3f, db3, x, out + 3, psum);
  k_fin   <<<1,    256, 0, stream>>>(acc, psum, out);
}